// Round 7
// baseline (1626.726 us; speedup 1.0000x reference)
//
#include <hip/hip_runtime.h>
#include <stdint.h>

typedef unsigned short u16;
typedef __bf16 bf16_t;
typedef bf16_t bf16x8 __attribute__((ext_vector_type(8)));
typedef float f32x4 __attribute__((ext_vector_type(4)));

#define Bdim 64
#define Tdim 256
#define Ddim 512
#define Hdim 1024
#define NGdim 4096

// ---------- helpers ----------
__device__ __forceinline__ u16 f2bf(float f) {
  union { float f; uint32_t u; } v; v.f = f;
  return (u16)((v.u + 0x7FFFu + ((v.u >> 16) & 1u)) >> 16);   // RNE
}
__device__ __forceinline__ float bf2f(u16 h) {
  union { uint32_t u; float f; } v; v.u = ((uint32_t)h) << 16;
  return v.f;
}
__device__ __forceinline__ float sigm(float x) { return 1.0f / (1.0f + __expf(-x)); }
__device__ __forceinline__ float tanh_fast(float x) { return 2.0f / (1.0f + __expf(-2.0f * x)) - 1.0f; }

__device__ __forceinline__ void load_lds16(const void* g, void* l) {
  __builtin_amdgcn_global_load_lds(
      (const __attribute__((address_space(1))) uint32_t*)g,
      (__attribute__((address_space(3))) uint32_t*)l, 16, 0, 0);
}
__device__ __forceinline__ f32x4 mfma_bf16(bf16x8 a, bf16x8 b, f32x4 c) {
  return __builtin_amdgcn_mfma_f32_16x16x32_bf16(a, b, c, 0, 0, 0);
}

// ---------- kernel 0: zero h double-buffer (bf16) + flags region ----------
__global__ void k_init(uint64_t* __restrict__ zreg) {
  zreg[blockIdx.x * 256 + threadIdx.x] = 0ull;   // 256 WGs x 256 x 8 B = 512 KB
}

// ---------- kernel 1: x fp32 -> bf16 ----------
__global__ void k_convert_x(const float* __restrict__ x, u16* __restrict__ xb) {
  const int i = (blockIdx.x * 256 + threadIdx.x) * 4;
  float4 v = *(const float4*)(x + i);
  union { u16 h[4]; uint2 v2; } p;
  p.h[0] = f2bf(v.x); p.h[1] = f2bf(v.y); p.h[2] = f2bf(v.z); p.h[3] = f2bf(v.w);
  *(uint2*)(xb + i) = p.v2;
}

// ---------- kernel 2: W[0:512][4096] fp32 -> WxT bf16 [4096][512] ----------
__global__ void k_transpose_wx(const float* __restrict__ W, u16* __restrict__ wxt) {
  __shared__ float tile[64][65];
  const int k0 = blockIdx.x * 64;   // 8 blocks
  const int n0 = blockIdx.y * 64;   // 64 blocks
  const int tn = threadIdx.x & 63, tk = threadIdx.x >> 6;
#pragma unroll
  for (int r = 0; r < 16; r++) {
    const int k = r * 4 + tk;
    tile[k][tn] = W[(size_t)(k0 + k) * NGdim + n0 + tn];
  }
  __syncthreads();
  for (int cid = threadIdx.x; cid < 512; cid += 256) {
    const int nl = cid >> 3, kc = cid & 7;
    union { u16 h[8]; uint4 v; } p;
#pragma unroll
    for (int j = 0; j < 8; j++) p.h[j] = f2bf(tile[kc * 8 + j][nl]);
    *(uint4*)(wxt + (size_t)(n0 + nl) * Ddim + k0 + kc * 8) = p.v;
  }
}

// ---------- kernel 3: W_h -> per-wg fragment layout whT[wg(64)][kt(32)][gate(4)][q(4)][hc(16)][ki(8)] ----------
// wg owns h-cols [wg*16, wg*16+16). Element (k, gate, hc) = W[(512+k)][gate*1024 + wg*16 + hc].
__global__ void k_prep_wh(const float* __restrict__ W, u16* __restrict__ whT) {
  const int wg = blockIdx.x;           // 0..63
  u16* dst = whT + (size_t)wg * 65536;
  const int gate = threadIdx.x & 3;
  const int hcq  = (threadIdx.x >> 2) & 3;
  const int kb   = threadIdx.x >> 4;   // 0..15
#pragma unroll 1
  for (int kk = 0; kk < 64; kk++) {
    const int k = kb * 64 + kk;
    const float4 wv = *(const float4*)(W + (size_t)(Ddim + k) * NGdim
                                         + gate * 1024 + wg * 16 + hcq * 4);
    const int kt = k >> 5, kl = k & 31, q = kl >> 3, ki = kl & 7;
    const int base = kt * 2048 + gate * 512 + q * 128 + ki;
    dst[base + (hcq * 4 + 0) * 8] = f2bf(wv.x);
    dst[base + (hcq * 4 + 1) * 8] = f2bf(wv.y);
    dst[base + (hcq * 4 + 2) * 8] = f2bf(wv.z);
    dst[base + (hcq * 4 + 3) * 8] = f2bf(wv.w);
  }
}

// ---------- kernel 4: XW = x @ Wx + b, output layout [t][1024 hcol][64 b][4 gates] bf16 ----------
__global__ __launch_bounds__(256) void k_gemm_xw(
    const u16* __restrict__ xb, const u16* __restrict__ wxt,
    const float* __restrict__ bias, u16* __restrict__ xw)
{
  __shared__ u16 smem[8192];        // 16 KB: sA [kg][128 m][8], sB [kg][128 j][8]
  const int Mtile = blockIdx.x;     // 0..127 (2 t's x 64 b)
  const int Ntile = blockIdx.y;     // 0..31
  const int g0 = Ntile * 8;
  const int tid = threadIdx.x;
  const int lane = tid & 63;
  const int wave = tid >> 6;
  const int wm = wave & 1, wn = wave >> 1;
  const int t0 = Mtile * 2;

  const size_t a_r0 = ((size_t)lane * Tdim + t0) * Ddim;
  const size_t a_r1 = ((size_t)lane * Tdim + t0 + 1) * Ddim;
  const int jc0 = lane, jc1 = 64 + lane;
  const int ng0 = (jc0 >> 5) * 1024 + (g0 + ((jc0 >> 2) & 7)) * 4 + (jc0 & 3);
  const int ng1 = (jc1 >> 5) * 1024 + (g0 + ((jc1 >> 2) & 7)) * 4 + (jc1 & 3);
  const size_t b_r0 = (size_t)ng0 * Ddim;
  const size_t b_r1 = (size_t)ng1 * Ddim;

  u16* sA = smem;
  u16* sB = smem + 4096;
  char* dA0 = (char*)sA + wave * 2048;
  char* dA1 = dA0 + 1024;
  char* dB0 = (char*)sB + wave * 2048;
  char* dB1 = dB0 + 1024;

  f32x4 zero4 = {0.f, 0.f, 0.f, 0.f};
  f32x4 acc[4][4];
#pragma unroll
  for (int i = 0; i < 4; i++)
#pragma unroll
    for (int j = 0; j < 4; j++) acc[i][j] = zero4;

  const int fa = (((lane >> 4) * 128) + wm * 64 + (lane & 15)) * 16;
  const int fb = (((lane >> 4) * 128) + wn * 64 + (lane & 15)) * 16;

  for (int k0 = 0; k0 < Ddim; k0 += 32) {
    const int koff = k0 + 8 * wave;
    __syncthreads();
    load_lds16(xb + a_r0 + koff, dA0);
    load_lds16(xb + a_r1 + koff, dA1);
    load_lds16(wxt + b_r0 + koff, dB0);
    load_lds16(wxt + b_r1 + koff, dB1);
    __syncthreads();
    bf16x8 af[4], bfr[4];
#pragma unroll
    for (int i = 0; i < 4; i++) {
      af[i]  = *(const bf16x8*)((const char*)sA + fa + i * 256);
      bfr[i] = *(const bf16x8*)((const char*)sB + fb + i * 256);
    }
#pragma unroll
    for (int mt = 0; mt < 4; mt++)
#pragma unroll
      for (int nt = 0; nt < 4; nt++)
        acc[mt][nt] = mfma_bf16(af[mt], bfr[nt], acc[mt][nt]);
  }

#pragma unroll 1
  for (int th = 0; th < 2; th++) {
    __syncthreads();
    if (wm == th) {
      const int q = lane >> 4, col0 = wn * 64 + (lane & 15);
#pragma unroll
      for (int mt = 0; mt < 4; mt++)
#pragma unroll
        for (int nt = 0; nt < 4; nt++)
#pragma unroll
          for (int i = 0; i < 4; i++)
            smem[(mt * 16 + q * 4 + i) * 128 + col0 + nt * 16] = f2bf(acc[mt][nt][i]);
    }
    __syncthreads();
    const int t = t0 + th;
    for (int cid = tid; cid < 512; cid += 256) {
      const int gsub = cid >> 6;
      const int b = cid & 63;
#pragma unroll
      for (int c = 0; c < 4; c++) {
        union { u16 h[4]; uint2 v; } pk;
#pragma unroll
        for (int gate = 0; gate < 4; gate++) {
          float v = bf2f(smem[b * 128 + gate * 32 + gsub * 4 + c])
                  + bias[gate * 1024 + (g0 + gsub) * 4 + c];
          pk.h[gate] = f2bf(v);
        }
        *(uint2*)(xw + (((size_t)t * 1024 + (g0 + gsub) * 4 + c) * 64 + b) * 4) = pk.v;
      }
    }
  }
}

// ---------- kernel 5: persistent LSTM, batch-partitioned (4 groups x 16 batches) ----------
// EXACT R3-verified kernel (passed, 5.1 us/step) + ONE delta: the xw gate read moves off
// wave 0's critical path. R3 issued a per-thread xw global load before the poll; the poll's
// first atomic load forces vmcnt(0) and drains that HBM load on the waiting path. Now waves
// 1-3 (idle during the poll) stage the WG's 256 gate-quads for t+1 into xwlds at loop
// bottom. Ordering: writes after the hpack barrier (= after all step-t xwlds reads);
// reads after the poll+zlds barriers. Everything else is byte-identical to R3.
__global__ __launch_bounds__(256, 1) void k_lstm_persist(
    const u16* __restrict__ whT, const u16* __restrict__ xw,
    const int* __restrict__ seq_len, u16* __restrict__ hbuf,
    uint32_t* __restrict__ flags, float* __restrict__ out)
{
  __shared__ float zlds[64 * 66];       // [wave*16+m][66 (pad)]
  __shared__ u16 hpack[16][16];         // [local batch][local hcol]
  __shared__ uint2 xwlds[16][16];       // [local batch][local hcol] 4 gates bf16
  const int gid   = blockIdx.x;
  const int g_grp = gid >> 6;           // batch group 0..3
  const int wg    = gid & 63;           // h-col owner within group
  const int tid   = threadIdx.x;
  const int lane  = tid & 63;
  const int wave  = tid >> 6;
  const int q     = lane >> 4;
  const int col   = lane & 15;
  const int b_t   = tid & 15;           // owned local batch
  const int hc_t  = tid >> 4;           // owned local hcol
  const int g16   = g_grp * 16;

  // stationary weights: wave covers K [wave*256, wave*256+256)
  bf16x8 bw[8][4];
  {
    const u16* wp = whT + (size_t)wg * 65536 + (size_t)(q * 16 + col) * 8;
#pragma unroll
    for (int kt = 0; kt < 8; kt++)
#pragma unroll
      for (int g = 0; g < 4; g++)
        bw[kt][g] = *(const bf16x8*)(wp + (wave * 8 + kt) * 2048 + g * 512);
  }

  const int slen = seq_len[g16 + b_t];
  float c_reg = 0.f, h_reg = 0.f;

  // A fragment base: batch row m = col, k = wave*256 + kt*32 + q*8 + j
  const u16* pa0 = hbuf + (size_t)(g16 + col) * Hdim + wave * 256 + q * 8;

  auto xw_addr = [&](int t, int hc, int b) {
    return (const uint2*)(xw + (((size_t)t * 1024 + wg * 16 + hc) * 64 + g16 + b) * 4);
  };

  // prologue: fill xwlds for t=0 (waves 1-3; ordered before reads by the t=0 zlds barrier)
  if (wave > 0) {
    const int idx = tid - 64;                     // 0..191
    const int b1 = idx & 15, hc1 = idx >> 4;      // hc 0..11
    xwlds[b1][hc1] = *xw_addr(0, hc1, b1);
    if (idx < 64) {
      const int b2 = idx & 15, hc2 = 12 + (idx >> 4);  // hc 12..15
      xwlds[b2][hc2] = *xw_addr(0, hc2, b2);
    }
  }

  for (int t = 0; t < Tdim; t++) {
    if (t > 0) {
      if (wave == 0) {
        const uint32_t gen = (uint32_t)t;
        const uint32_t* fp = flags + g_grp * 64 + lane;   // 64 flags = 4 lines
        uint32_t f;
        do {
          f = __hip_atomic_load(fp, __ATOMIC_RELAXED, __HIP_MEMORY_SCOPE_AGENT);
        } while (!__all(f >= gen));
      }
      __syncthreads();   // no fence: h loads below bypass L1/L2 (sc0 sc1)
    }

    // coherent (LLC-direct) h loads: 8 x 16 B per lane = wave's 16x256 A-slice
    const u16* pa_t = pa0 + (size_t)(t & 1) * (Bdim * Hdim);
    f32x4 av[8];
#pragma unroll
    for (int kt = 0; kt < 8; kt++)
      asm volatile("global_load_dwordx4 %0, %1, off sc0 sc1"
                   : "=v"(av[kt]) : "v"(pa_t + kt * 32));

    asm volatile("s_waitcnt vmcnt(0)" ::: "memory");
    __builtin_amdgcn_sched_barrier(0);   // rule #18: keep MFMAs behind the wait

    const f32x4 zero4 = {0.f, 0.f, 0.f, 0.f};
    f32x4 acc[4] = {zero4, zero4, zero4, zero4};
#pragma unroll
    for (int kt = 0; kt < 8; kt++)
#pragma unroll
      for (int g = 0; g < 4; g++)
        acc[g] = mfma_bf16(__builtin_bit_cast(bf16x8, av[kt]), bw[kt][g], acc[g]);

    // partial z -> LDS (C/D: n = lane&15, m = q*4+i); stride 66 => ~2-way (free)
#pragma unroll
    for (int g = 0; g < 4; g++)
#pragma unroll
      for (int i = 0; i < 4; i++)
        zlds[(wave * 16 + q * 4 + i) * 66 + g * 16 + col] = acc[g][i];
    __syncthreads();

    // cross-wave K-reduction; thread owns (b_t, wg*16 + hc_t)
    float zg[4];
#pragma unroll
    for (int g = 0; g < 4; g++) {
      float s = 0.f;
#pragma unroll
      for (int w = 0; w < 4; w++)
        s += zlds[(w * 16 + b_t) * 66 + g * 16 + hc_t];
      zg[g] = s;
    }
    union { uint2 v; u16 h[4]; } xp; xp.v = xwlds[b_t][hc_t];
    const float zi = zg[0] + bf2f(xp.h[0]);
    const float zj = zg[1] + bf2f(xp.h[1]);
    const float zf = zg[2] + bf2f(xp.h[2]);
    const float zo = zg[3] + bf2f(xp.h[3]);
    if (t < slen) {
      c_reg = c_reg * sigm(zf + 1.0f) + sigm(zi) * tanh_fast(zj);
      h_reg = tanh_fast(c_reg) * sigm(zo);
    }

    if (t == Tdim - 1) break;   // final h stays in registers

    // publish h slice (512 B): write-through agent stores, drain, then flag
    hpack[b_t][hc_t] = f2bf(h_reg);
    __syncthreads();
    if (wave == 0) {
      u16* hdst = hbuf + (size_t)((t + 1) & 1) * (Bdim * Hdim);
      const int pb = lane >> 2, ph = (lane & 3) * 4;
      const uint64_t pk = *(const uint64_t*)(&hpack[pb][ph]);
      __hip_atomic_store((uint64_t*)(hdst + (size_t)(g16 + pb) * Hdim + wg * 16 + ph), pk,
                         __ATOMIC_RELAXED, __HIP_MEMORY_SCOPE_AGENT);
      asm volatile("s_waitcnt vmcnt(0)" ::: "memory");   // h at coherence point
      if (lane == 0)
        __hip_atomic_store(flags + gid, (uint32_t)(t + 1),
                           __ATOMIC_RELAXED, __HIP_MEMORY_SCOPE_AGENT);
    }
    // loop bottom: waves 1-3 prefetch xw(t+1) into LDS (hpack barrier ordered the
    // rewrite after all step-t reads; the t+1 poll barrier orders it before reads)
    if (wave > 0) {
      const int idx = tid - 64;
      const int b1 = idx & 15, hc1 = idx >> 4;
      xwlds[b1][hc1] = *xw_addr(t + 1, hc1, b1);
      if (idx < 64) {
        const int b2 = idx & 15, hc2 = 12 + (idx >> 4);
        xwlds[b2][hc2] = *xw_addr(t + 1, hc2, b2);
      }
    }
  }

  out[(size_t)(g16 + b_t) * Hdim + wg * 16 + hc_t] = h_reg;
}

// ---------- host ----------
extern "C" void kernel_launch(void* const* d_in, const int* in_sizes, int n_in,
                              void* d_out, int out_size, void* d_ws, size_t ws_size,
                              hipStream_t stream) {
  (void)in_sizes; (void)n_in; (void)out_size; (void)ws_size;
  const float* x       = (const float*)d_in[0];
  const int*   seq_len = (const int*)d_in[1];
  const float* W       = (const float*)d_in[2];
  const float* bias    = (const float*)d_in[3];
  float* out = (float*)d_out;

  char* ws = (char*)d_ws;
  u16*   xw   = (u16*)(ws);                                  // 128 MB [t][hcol][b][gate] bf16
  u16*   xb   = (u16*)(ws + (size_t)134217728);              // 16 MB  x bf16 [B][T][D]
  u16*   wxt  = (u16*)(ws + (size_t)150994944);              // 4 MB   WxT bf16 [4096][512]
  u16*   whT  = (u16*)(ws + (size_t)155189248);              // 8 MB   W_h fragments [64][65536]
  char*  hreg = ws + (size_t)163577856;                      // 256 KB h dbuf + flags
  u16*   hbuf = (u16*)hreg;
  uint32_t* flags = (uint32_t*)(hreg + 262144);              // 256 x 4 B packed

  k_init<<<dim3(256), dim3(256), 0, stream>>>((uint64_t*)hreg);          // zero h dbuf + flags
  k_convert_x<<<dim3(8192), dim3(256), 0, stream>>>(x, xb);
  k_transpose_wx<<<dim3(8, 64), dim3(256), 0, stream>>>(W, wxt);
  k_prep_wh<<<dim3(64), dim3(256), 0, stream>>>(W, whT);
  k_gemm_xw<<<dim3(128, 32), dim3(256), 0, stream>>>(xb, wxt, bias, xw);

  {
    void* kargs[] = { (void*)&whT, (void*)&xw, (void*)&seq_len,
                      (void*)&hbuf, (void*)&flags, (void*)&out };
    hipLaunchCooperativeKernel((const void*)k_lstm_persist, dim3(256), dim3(256),
                               kargs, 0, stream);
  }
}

// Round 9
// 1485.634 us; speedup vs baseline: 1.0950x; 1.0950x over previous
//
#include <hip/hip_runtime.h>
#include <stdint.h>

typedef unsigned short u16;
typedef __bf16 bf16_t;
typedef bf16_t bf16x8 __attribute__((ext_vector_type(8)));
typedef float f32x4 __attribute__((ext_vector_type(4)));

#define Bdim 64
#define Tdim 256
#define Ddim 512
#define Hdim 1024
#define NGdim 4096

// ---------- helpers ----------
__device__ __forceinline__ u16 f2bf(float f) {
  union { float f; uint32_t u; } v; v.f = f;
  return (u16)((v.u + 0x7FFFu + ((v.u >> 16) & 1u)) >> 16);   // RNE
}
__device__ __forceinline__ float bf2f(u16 h) {
  union { uint32_t u; float f; } v; v.u = ((uint32_t)h) << 16;
  return v.f;
}
__device__ __forceinline__ float sigm(float x) { return 1.0f / (1.0f + __expf(-x)); }
__device__ __forceinline__ float tanh_fast(float x) { return 2.0f / (1.0f + __expf(-2.0f * x)) - 1.0f; }

__device__ __forceinline__ void load_lds16(const void* g, void* l) {
  __builtin_amdgcn_global_load_lds(
      (const __attribute__((address_space(1))) uint32_t*)g,
      (__attribute__((address_space(3))) uint32_t*)l, 16, 0, 0);
}
__device__ __forceinline__ f32x4 mfma_bf16(bf16x8 a, bf16x8 b, f32x4 c) {
  return __builtin_amdgcn_mfma_f32_16x16x32_bf16(a, b, c, 0, 0, 0);
}

// ---------- kernel 0: zero h double-buffer (bf16) + flags region ----------
__global__ void k_init(uint64_t* __restrict__ zreg) {
  zreg[blockIdx.x * 256 + threadIdx.x] = 0ull;   // 256 WGs x 256 x 8 B = 512 KB
}

// ---------- kernel 1: x fp32 -> bf16 ----------
__global__ void k_convert_x(const float* __restrict__ x, u16* __restrict__ xb) {
  const int i = (blockIdx.x * 256 + threadIdx.x) * 4;
  float4 v = *(const float4*)(x + i);
  union { u16 h[4]; uint2 v2; } p;
  p.h[0] = f2bf(v.x); p.h[1] = f2bf(v.y); p.h[2] = f2bf(v.z); p.h[3] = f2bf(v.w);
  *(uint2*)(xb + i) = p.v2;
}

// ---------- kernel 2: W[0:512][4096] fp32 -> WxT bf16 [4096][512] ----------
__global__ void k_transpose_wx(const float* __restrict__ W, u16* __restrict__ wxt) {
  __shared__ float tile[64][65];
  const int k0 = blockIdx.x * 64;   // 8 blocks
  const int n0 = blockIdx.y * 64;   // 64 blocks
  const int tn = threadIdx.x & 63, tk = threadIdx.x >> 6;
#pragma unroll
  for (int r = 0; r < 16; r++) {
    const int k = r * 4 + tk;
    tile[k][tn] = W[(size_t)(k0 + k) * NGdim + n0 + tn];
  }
  __syncthreads();
  for (int cid = threadIdx.x; cid < 512; cid += 256) {
    const int nl = cid >> 3, kc = cid & 7;
    union { u16 h[8]; uint4 v; } p;
#pragma unroll
    for (int j = 0; j < 8; j++) p.h[j] = f2bf(tile[kc * 8 + j][nl]);
    *(uint4*)(wxt + (size_t)(n0 + nl) * Ddim + k0 + kc * 8) = p.v;
  }
}

// ---------- kernel 3: W_h -> per-wg fragment layout whT[wg(64)][kt(32)][gate(4)][q(4)][hc(16)][ki(8)] ----------
// wg owns h-cols [wg*16, wg*16+16). Element (k, gate, hc) = W[(512+k)][gate*1024 + wg*16 + hc].
__global__ void k_prep_wh(const float* __restrict__ W, u16* __restrict__ whT) {
  const int wg = blockIdx.x;           // 0..63
  u16* dst = whT + (size_t)wg * 65536;
  const int gate = threadIdx.x & 3;
  const int hcq  = (threadIdx.x >> 2) & 3;
  const int kb   = threadIdx.x >> 4;   // 0..15
#pragma unroll 1
  for (int kk = 0; kk < 64; kk++) {
    const int k = kb * 64 + kk;
    const float4 wv = *(const float4*)(W + (size_t)(Ddim + k) * NGdim
                                         + gate * 1024 + wg * 16 + hcq * 4);
    const int kt = k >> 5, kl = k & 31, q = kl >> 3, ki = kl & 7;
    const int base = kt * 2048 + gate * 512 + q * 128 + ki;
    dst[base + (hcq * 4 + 0) * 8] = f2bf(wv.x);
    dst[base + (hcq * 4 + 1) * 8] = f2bf(wv.y);
    dst[base + (hcq * 4 + 2) * 8] = f2bf(wv.z);
    dst[base + (hcq * 4 + 3) * 8] = f2bf(wv.w);
  }
}

// ---------- kernel 4: XW = x @ Wx + b, output layout [t][1024 hcol][64 b][4 gates] bf16 ----------
__global__ __launch_bounds__(256) void k_gemm_xw(
    const u16* __restrict__ xb, const u16* __restrict__ wxt,
    const float* __restrict__ bias, u16* __restrict__ xw)
{
  __shared__ u16 smem[8192];        // 16 KB: sA [kg][128 m][8], sB [kg][128 j][8]
  const int Mtile = blockIdx.x;     // 0..127 (2 t's x 64 b)
  const int Ntile = blockIdx.y;     // 0..31
  const int g0 = Ntile * 8;
  const int tid = threadIdx.x;
  const int lane = tid & 63;
  const int wave = tid >> 6;
  const int wm = wave & 1, wn = wave >> 1;
  const int t0 = Mtile * 2;

  const size_t a_r0 = ((size_t)lane * Tdim + t0) * Ddim;
  const size_t a_r1 = ((size_t)lane * Tdim + t0 + 1) * Ddim;
  const int jc0 = lane, jc1 = 64 + lane;
  const int ng0 = (jc0 >> 5) * 1024 + (g0 + ((jc0 >> 2) & 7)) * 4 + (jc0 & 3);
  const int ng1 = (jc1 >> 5) * 1024 + (g0 + ((jc1 >> 2) & 7)) * 4 + (jc1 & 3);
  const size_t b_r0 = (size_t)ng0 * Ddim;
  const size_t b_r1 = (size_t)ng1 * Ddim;

  u16* sA = smem;
  u16* sB = smem + 4096;
  char* dA0 = (char*)sA + wave * 2048;
  char* dA1 = dA0 + 1024;
  char* dB0 = (char*)sB + wave * 2048;
  char* dB1 = dB0 + 1024;

  f32x4 zero4 = {0.f, 0.f, 0.f, 0.f};
  f32x4 acc[4][4];
#pragma unroll
  for (int i = 0; i < 4; i++)
#pragma unroll
    for (int j = 0; j < 4; j++) acc[i][j] = zero4;

  const int fa = (((lane >> 4) * 128) + wm * 64 + (lane & 15)) * 16;
  const int fb = (((lane >> 4) * 128) + wn * 64 + (lane & 15)) * 16;

  for (int k0 = 0; k0 < Ddim; k0 += 32) {
    const int koff = k0 + 8 * wave;
    __syncthreads();
    load_lds16(xb + a_r0 + koff, dA0);
    load_lds16(xb + a_r1 + koff, dA1);
    load_lds16(wxt + b_r0 + koff, dB0);
    load_lds16(wxt + b_r1 + koff, dB1);
    __syncthreads();
    bf16x8 af[4], bfr[4];
#pragma unroll
    for (int i = 0; i < 4; i++) {
      af[i]  = *(const bf16x8*)((const char*)sA + fa + i * 256);
      bfr[i] = *(const bf16x8*)((const char*)sB + fb + i * 256);
    }
#pragma unroll
    for (int mt = 0; mt < 4; mt++)
#pragma unroll
      for (int nt = 0; nt < 4; nt++)
        acc[mt][nt] = mfma_bf16(af[mt], bfr[nt], acc[mt][nt]);
  }

#pragma unroll 1
  for (int th = 0; th < 2; th++) {
    __syncthreads();
    if (wm == th) {
      const int q = lane >> 4, col0 = wn * 64 + (lane & 15);
#pragma unroll
      for (int mt = 0; mt < 4; mt++)
#pragma unroll
        for (int nt = 0; nt < 4; nt++)
#pragma unroll
          for (int i = 0; i < 4; i++)
            smem[(mt * 16 + q * 4 + i) * 128 + col0 + nt * 16] = f2bf(acc[mt][nt][i]);
    }
    __syncthreads();
    const int t = t0 + th;
    for (int cid = tid; cid < 512; cid += 256) {
      const int gsub = cid >> 6;
      const int b = cid & 63;
#pragma unroll
      for (int c = 0; c < 4; c++) {
        union { u16 h[4]; uint2 v; } pk;
#pragma unroll
        for (int gate = 0; gate < 4; gate++) {
          float v = bf2f(smem[b * 128 + gate * 32 + gsub * 4 + c])
                  + bias[gate * 1024 + (g0 + gsub) * 4 + c];
          pk.h[gate] = f2bf(v);
        }
        *(uint2*)(xw + (((size_t)t * 1024 + (g0 + gsub) * 4 + c) * 64 + b) * 4) = pk.v;
      }
    }
  }
}

// ---------- kernel 5: persistent LSTM, 4 groups x 16 batches (R7-verified sync structure) ----------
// Bisect of R8: keep the R7-verified full-group poll (wave 0 polls all 64 group flags, then
// __syncthreads) — drop R8's per-wave polling (suspected race carrier). Keep R8's two
// PASSIVE deltas (math verified by R8's first-pass success):
//  1) producer-major h layout hbuf[parity][group(4)][producer wg(64)][16 b][16 c]:
//     producer publishes one contiguous 512 B block (4 full lines vs 16 partial);
//     consumer av[kt] load = contiguous, 1 KB/instr wave coalescing.
//     local k = kt*32 + q*8 + j -> producer wave*16 + kt*2 + (q>>1), elem c = (q&1)*8 + j.
//  2) split vmcnt: vmcnt(4) -> MFMA kt0..3 -> vmcnt(0) -> kt4..7 (wave-local, m135 semantics).
__global__ __launch_bounds__(256, 1) void k_lstm_persist(
    const u16* __restrict__ whT, const u16* __restrict__ xw,
    const int* __restrict__ seq_len, u16* __restrict__ hbuf,
    uint32_t* __restrict__ flags, float* __restrict__ out)
{
  __shared__ float zlds[64 * 66];       // [wave*16+m][66 (pad)]
  __shared__ __align__(8) u16 hpack[16][16];   // [local batch][local hcol]
  __shared__ uint2 xwlds[16][16];       // [local batch][local hcol] 4 gates bf16
  const int gid   = blockIdx.x;
  const int g_grp = gid >> 6;           // batch group 0..3
  const int wg    = gid & 63;           // h-col owner within group
  const int tid   = threadIdx.x;
  const int lane  = tid & 63;
  const int wave  = tid >> 6;
  const int q     = lane >> 4;
  const int col   = lane & 15;
  const int b_t   = tid & 15;           // owned local batch
  const int hc_t  = tid >> 4;           // owned local hcol
  const int g16   = g_grp * 16;

  // stationary weights: wave covers K [wave*256, wave*256+256)
  bf16x8 bw[8][4];
  {
    const u16* wp = whT + (size_t)wg * 65536 + (size_t)(q * 16 + col) * 8;
#pragma unroll
    for (int kt = 0; kt < 8; kt++)
#pragma unroll
      for (int g = 0; g < 4; g++)
        bw[kt][g] = *(const bf16x8*)(wp + (wave * 8 + kt) * 2048 + g * 512);
  }

  const int slen = seq_len[g16 + b_t];
  float c_reg = 0.f, h_reg = 0.f;

  // producer-major A base: producer p = wave*16 + kt*2 + (q>>1), batch = col,
  // elem (q&1)*8 + j. u16 offset: parity*65536 + g_grp*16384 + p*256 + col*16 + (q&1)*8
  const u16* pa0 = hbuf + (size_t)g_grp * 16384
                 + (size_t)(wave * 16 + (q >> 1)) * 256 + col * 16 + (q & 1) * 8;

  auto xw_addr = [&](int t, int hc, int b) {
    return (const uint2*)(xw + (((size_t)t * 1024 + wg * 16 + hc) * 64 + g16 + b) * 4);
  };

  // prologue: fill xwlds for t=0 (waves 1-3; ordered before reads by the t=0 zlds barrier)
  if (wave > 0) {
    const int idx = tid - 64;                     // 0..191
    const int b1 = idx & 15, hc1 = idx >> 4;      // hc 0..11
    xwlds[b1][hc1] = *xw_addr(0, hc1, b1);
    if (idx < 64) {
      const int b2 = idx & 15, hc2 = 12 + (idx >> 4);  // hc 12..15
      xwlds[b2][hc2] = *xw_addr(0, hc2, b2);
    }
  }

  for (int t = 0; t < Tdim; t++) {
    if (t > 0) {
      if (wave == 0) {
        const uint32_t gen = (uint32_t)t;
        const uint32_t* fp = flags + g_grp * 64 + lane;   // all 64 group flags
        uint32_t f;
        do {
          f = __hip_atomic_load(fp, __ATOMIC_RELAXED, __HIP_MEMORY_SCOPE_AGENT);
        } while (!__all(f >= gen));
      }
      __syncthreads();   // R7-verified: barrier between flag observation and h reads
    }

    // coherent (LLC-direct) h loads, producer-major contiguous; av[kt] = 16 B/lane
    const u16* pa_t = pa0 + (size_t)(t & 1) * 65536;
    f32x4 av[8];
#pragma unroll
    for (int kt = 0; kt < 8; kt++)
      asm volatile("global_load_dwordx4 %0, %1, off sc0 sc1"
                   : "=v"(av[kt]) : "v"(pa_t + kt * 512));

    const f32x4 zero4 = {0.f, 0.f, 0.f, 0.f};
    f32x4 acc[4] = {zero4, zero4, zero4, zero4};
    asm volatile("s_waitcnt vmcnt(4)" ::: "memory");
    __builtin_amdgcn_sched_barrier(0);   // rule #18: keep MFMAs behind the wait
#pragma unroll
    for (int kt = 0; kt < 4; kt++)
#pragma unroll
      for (int g = 0; g < 4; g++)
        acc[g] = mfma_bf16(__builtin_bit_cast(bf16x8, av[kt]), bw[kt][g], acc[g]);
    asm volatile("s_waitcnt vmcnt(0)" ::: "memory");
    __builtin_amdgcn_sched_barrier(0);
#pragma unroll
    for (int kt = 4; kt < 8; kt++)
#pragma unroll
      for (int g = 0; g < 4; g++)
        acc[g] = mfma_bf16(__builtin_bit_cast(bf16x8, av[kt]), bw[kt][g], acc[g]);

    // partial z -> LDS (C/D: n = lane&15, m = q*4+i); stride 66 => ~2-way (free)
#pragma unroll
    for (int g = 0; g < 4; g++)
#pragma unroll
      for (int i = 0; i < 4; i++)
        zlds[(wave * 16 + q * 4 + i) * 66 + g * 16 + col] = acc[g][i];
    __syncthreads();

    // cross-wave K-reduction; thread owns (b_t, wg*16 + hc_t)
    float zg[4];
#pragma unroll
    for (int g = 0; g < 4; g++) {
      float s = 0.f;
#pragma unroll
      for (int w = 0; w < 4; w++)
        s += zlds[(w * 16 + b_t) * 66 + g * 16 + hc_t];
      zg[g] = s;
    }
    union { uint2 v; u16 h[4]; } xp; xp.v = xwlds[b_t][hc_t];
    const float zi = zg[0] + bf2f(xp.h[0]);
    const float zj = zg[1] + bf2f(xp.h[1]);
    const float zf = zg[2] + bf2f(xp.h[2]);
    const float zo = zg[3] + bf2f(xp.h[3]);
    if (t < slen) {
      c_reg = c_reg * sigm(zf + 1.0f) + sigm(zi) * tanh_fast(zj);
      h_reg = tanh_fast(c_reg) * sigm(zo);
    }

    if (t == Tdim - 1) break;   // final h stays in registers

    // publish h slice: ONE contiguous 512 B block (4 full lines), drain, then flag
    hpack[b_t][hc_t] = f2bf(h_reg);
    __syncthreads();            // also orders: all zlds/xwlds reads done before rewrites
    if (wave == 0) {
      const int pb = lane >> 2, ph = (lane & 3) * 4;
      const uint64_t pk = *(const uint64_t*)(&hpack[pb][ph]);
      u16* daddr = hbuf + (size_t)((t + 1) & 1) * 65536 + g_grp * 16384
                 + wg * 256 + pb * 16 + ph;
      __hip_atomic_store((uint64_t*)daddr, pk,
                         __ATOMIC_RELAXED, __HIP_MEMORY_SCOPE_AGENT);
      asm volatile("s_waitcnt vmcnt(0)" ::: "memory");   // h at coherence point
      if (lane == 0)
        __hip_atomic_store(flags + gid, (uint32_t)(t + 1),
                           __ATOMIC_RELAXED, __HIP_MEMORY_SCOPE_AGENT);
    }
    // loop bottom: waves 1-3 prefetch xw(t+1) into LDS (hpack barrier ordered the
    // rewrite after all step-t reads; the t+1 poll barrier orders it before reads)
    if (wave > 0) {
      const int idx = tid - 64;
      const int b1 = idx & 15, hc1 = idx >> 4;
      xwlds[b1][hc1] = *xw_addr(t + 1, hc1, b1);
      if (idx < 64) {
        const int b2 = idx & 15, hc2 = 12 + (idx >> 4);
        xwlds[b2][hc2] = *xw_addr(t + 1, hc2, b2);
      }
    }
  }

  out[(size_t)(g16 + b_t) * Hdim + wg * 16 + hc_t] = h_reg;
}

// ---------- host ----------
extern "C" void kernel_launch(void* const* d_in, const int* in_sizes, int n_in,
                              void* d_out, int out_size, void* d_ws, size_t ws_size,
                              hipStream_t stream) {
  (void)in_sizes; (void)n_in; (void)out_size; (void)ws_size;
  const float* x       = (const float*)d_in[0];
  const int*   seq_len = (const int*)d_in[1];
  const float* W       = (const float*)d_in[2];
  const float* bias    = (const float*)d_in[3];
  float* out = (float*)d_out;

  char* ws = (char*)d_ws;
  u16*   xw   = (u16*)(ws);                                  // 128 MB [t][hcol][b][gate] bf16
  u16*   xb   = (u16*)(ws + (size_t)134217728);              // 16 MB  x bf16 [B][T][D]
  u16*   wxt  = (u16*)(ws + (size_t)150994944);              // 4 MB   WxT bf16 [4096][512]
  u16*   whT  = (u16*)(ws + (size_t)155189248);              // 8 MB   W_h fragments [64][65536]
  char*  hreg = ws + (size_t)163577856;                      // 256 KB h dbuf (producer-major) + flags
  u16*   hbuf = (u16*)hreg;
  uint32_t* flags = (uint32_t*)(hreg + 262144);              // 256 x 4 B packed

  k_init<<<dim3(256), dim3(256), 0, stream>>>((uint64_t*)hreg);          // zero h dbuf + flags
  k_convert_x<<<dim3(8192), dim3(256), 0, stream>>>(x, xb);
  k_transpose_wx<<<dim3(8, 64), dim3(256), 0, stream>>>(W, wxt);
  k_prep_wh<<<dim3(64), dim3(256), 0, stream>>>(W, whT);
  k_gemm_xw<<<dim3(128, 32), dim3(256), 0, stream>>>(xb, wxt, bias, xw);

  {
    void* kargs[] = { (void*)&whT, (void*)&xw, (void*)&seq_len,
                      (void*)&hbuf, (void*)&flags, (void*)&out };
    hipLaunchCooperativeKernel((const void*)k_lstm_persist, dim3(256), dim3(256),
                               kargs, 0, stream);
  }
}

// Round 10
// 1443.035 us; speedup vs baseline: 1.1273x; 1.0295x over previous
//
#include <hip/hip_runtime.h>
#include <stdint.h>

typedef unsigned short u16;
typedef __bf16 bf16_t;
typedef bf16_t bf16x8 __attribute__((ext_vector_type(8)));
typedef float f32x4 __attribute__((ext_vector_type(4)));

#define Bdim 64
#define Tdim 256
#define Ddim 512
#define Hdim 1024
#define NGdim 4096

// ---------- helpers ----------
__device__ __forceinline__ u16 f2bf(float f) {
  union { float f; uint32_t u; } v; v.f = f;
  return (u16)((v.u + 0x7FFFu + ((v.u >> 16) & 1u)) >> 16);   // RNE
}
__device__ __forceinline__ float bf2f(u16 h) {
  union { uint32_t u; float f; } v; v.u = ((uint32_t)h) << 16;
  return v.f;
}
__device__ __forceinline__ float sigm(float x) { return 1.0f / (1.0f + __expf(-x)); }
__device__ __forceinline__ float tanh_fast(float x) { return 2.0f / (1.0f + __expf(-2.0f * x)) - 1.0f; }

__device__ __forceinline__ void load_lds16(const void* g, void* l) {
  __builtin_amdgcn_global_load_lds(
      (const __attribute__((address_space(1))) uint32_t*)g,
      (__attribute__((address_space(3))) uint32_t*)l, 16, 0, 0);
}
__device__ __forceinline__ f32x4 mfma_bf16(bf16x8 a, bf16x8 b, f32x4 c) {
  return __builtin_amdgcn_mfma_f32_16x16x32_bf16(a, b, c, 0, 0, 0);
}

// ---------- kernel 0: zero h double-buffer (bf16) + flags region ----------
__global__ void k_init(uint64_t* __restrict__ zreg) {
  zreg[blockIdx.x * 256 + threadIdx.x] = 0ull;   // 256 WGs x 256 x 8 B = 512 KB
}

// ---------- kernel 1: x fp32 [b][t][d] -> xb2 bf16 M-major [t*64+b][512] ----------
// M-major rows make the GEMM A-tile 128 CONTIGUOUS rows (was 256-KB-strided gather).
__global__ void k_convert_x(const float* __restrict__ x, u16* __restrict__ xb) {
  const int i = (blockIdx.x * 256 + threadIdx.x) * 4;
  const int d = i & 511;
  const int t = (i >> 9) & 255;
  const int b = i >> 17;
  float4 v = *(const float4*)(x + i);
  union { u16 h[4]; uint2 v2; } p;
  p.h[0] = f2bf(v.x); p.h[1] = f2bf(v.y); p.h[2] = f2bf(v.z); p.h[3] = f2bf(v.w);
  *(uint2*)(xb + (size_t)(t * 64 + b) * 512 + d) = p.v2;
}

// ---------- kernel 2: W[0:512][4096] fp32 -> wxt2 bf16, PRE-PERMUTED into GEMM row order ----------
// Row p = Ntile*128 + j holds W_x^T[ng] where ng = (j>>5)*1024 + (Ntile*8 + ((j>>2)&7))*4 + (j&3).
// Inverse (verified bijective): Ntile = ((ng>>2)&255)>>3; j = (ng>>10)*32 + ((ng>>2)&7)*4 + (ng&3).
__global__ void k_transpose_wx(const float* __restrict__ W, u16* __restrict__ wxt) {
  __shared__ float tile[64][65];
  const int k0 = blockIdx.x * 64;   // 8 blocks
  const int n0 = blockIdx.y * 64;   // 64 blocks
  const int tn = threadIdx.x & 63, tk = threadIdx.x >> 6;
#pragma unroll
  for (int r = 0; r < 16; r++) {
    const int k = r * 4 + tk;
    tile[k][tn] = W[(size_t)(k0 + k) * NGdim + n0 + tn];
  }
  __syncthreads();
  for (int cid = threadIdx.x; cid < 512; cid += 256) {
    const int nl = cid >> 3, kc = cid & 7;
    union { u16 h[8]; uint4 v; } p;
#pragma unroll
    for (int j = 0; j < 8; j++) p.h[j] = f2bf(tile[kc * 8 + j][nl]);
    const int ng = n0 + nl;
    const int prow = (((ng >> 2) & 255) >> 3) * 128
                   + ((ng >> 10) << 5) + (((ng >> 2) & 7) << 2) + (ng & 3);
    *(uint4*)(wxt + (size_t)prow * Ddim + k0 + kc * 8) = p.v;
  }
}

// ---------- kernel 3: W_h -> per-wg fragment layout whT[wg(64)][kt(32)][gate(4)][q(4)][hc(16)][ki(8)] ----------
// wg owns h-cols [wg*16, wg*16+16). Element (k, gate, hc) = W[(512+k)][gate*1024 + wg*16 + hc].
__global__ void k_prep_wh(const float* __restrict__ W, u16* __restrict__ whT) {
  const int wg = blockIdx.x;           // 0..63
  u16* dst = whT + (size_t)wg * 65536;
  const int gate = threadIdx.x & 3;
  const int hcq  = (threadIdx.x >> 2) & 3;
  const int kb   = threadIdx.x >> 4;   // 0..15
#pragma unroll 1
  for (int kk = 0; kk < 64; kk++) {
    const int k = kb * 64 + kk;
    const float4 wv = *(const float4*)(W + (size_t)(Ddim + k) * NGdim
                                         + gate * 1024 + wg * 16 + hcq * 4);
    const int kt = k >> 5, kl = k & 31, q = kl >> 3, ki = kl & 7;
    const int base = kt * 2048 + gate * 512 + q * 128 + ki;
    dst[base + (hcq * 4 + 0) * 8] = f2bf(wv.x);
    dst[base + (hcq * 4 + 1) * 8] = f2bf(wv.y);
    dst[base + (hcq * 4 + 2) * 8] = f2bf(wv.z);
    dst[base + (hcq * 4 + 3) * 8] = f2bf(wv.w);
  }
}

// ---------- kernel 4: XW = x @ Wx + b, output layout [t][1024 hcol][64 b][4 gates] bf16 ----------
// Reworked staging: A = xb2 rows [Mtile*128, +128) (contiguous), B = wxt2 rows [Ntile*128, +128)
// (pre-permuted). LDS tiles row-major [128][32]; gload_lds lane-linear dest == [row][k] layout
// (lane l -> row l>>2, kg l&3: 32*(l>>2) + 8*(l&3) == 8*l). Source = 64-B bursts (4 lanes/row).
// Frag reads: contiguous 1 KB per wave ds_read_b128, conflict-free. MFMA + epilogue unchanged.
__global__ __launch_bounds__(256) void k_gemm_xw(
    const u16* __restrict__ xb, const u16* __restrict__ wxt,
    const float* __restrict__ bias, u16* __restrict__ xw)
{
  __shared__ u16 smem[8192];        // 16 KB: sA [128 m][32 k], sB [128 j][32 k]
  const int Mtile = blockIdx.x;     // 0..127 (2 t's x 64 b)
  const int Ntile = blockIdx.y;     // 0..31
  const int g0 = Ntile * 8;
  const int tid = threadIdx.x;
  const int lane = tid & 63;
  const int wave = tid >> 6;
  const int wm = wave & 1, wn = wave >> 1;
  const int t0 = Mtile * 2;

  u16* sA = smem;
  u16* sB = smem + 4096;
  // staging: wave w owns rows [w*32, w*32+32) of both tiles; lane l -> (row w*32 + l>>2, kg l&3)
  const size_t a_src = ((size_t)Mtile * 128 + wave * 32 + (lane >> 2)) * Ddim + (lane & 3) * 8;
  const size_t b_src = ((size_t)Ntile * 128 + wave * 32 + (lane >> 2)) * Ddim + (lane & 3) * 8;
  char* dA0 = (char*)sA + wave * 2048;          // rows w*32 + 0..15
  char* dA1 = dA0 + 1024;                       // rows w*32 + 16..31
  char* dB0 = (char*)sB + wave * 2048;
  char* dB1 = dB0 + 1024;

  f32x4 zero4 = {0.f, 0.f, 0.f, 0.f};
  f32x4 acc[4][4];
#pragma unroll
  for (int i = 0; i < 4; i++)
#pragma unroll
    for (int j = 0; j < 4; j++) acc[i][j] = zero4;

  // frag read base: row-major [row][32 k]; af[i] row = wm*64 + i*16 + col, k = q*8..+8
  const int fa = ((wm * 64 + (lane & 15)) * 32 + (lane >> 4) * 8) * 2;   // bytes
  const int fb = ((wn * 64 + (lane & 15)) * 32 + (lane >> 4) * 8) * 2;

  for (int k0 = 0; k0 < Ddim; k0 += 32) {
    __syncthreads();
    load_lds16(xb + a_src + k0, dA0);
    load_lds16(xb + a_src + 16 * Ddim + k0, dA1);
    load_lds16(wxt + b_src + k0, dB0);
    load_lds16(wxt + b_src + 16 * Ddim + k0, dB1);
    __syncthreads();
    bf16x8 af[4], bfr[4];
#pragma unroll
    for (int i = 0; i < 4; i++) {
      af[i]  = *(const bf16x8*)((const char*)sA + fa + i * 1024);
      bfr[i] = *(const bf16x8*)((const char*)sB + fb + i * 1024);
    }
#pragma unroll
    for (int mt = 0; mt < 4; mt++)
#pragma unroll
      for (int nt = 0; nt < 4; nt++)
        acc[mt][nt] = mfma_bf16(af[mt], bfr[nt], acc[mt][nt]);
  }

#pragma unroll 1
  for (int th = 0; th < 2; th++) {
    __syncthreads();
    if (wm == th) {
      const int q = lane >> 4, col0 = wn * 64 + (lane & 15);
#pragma unroll
      for (int mt = 0; mt < 4; mt++)
#pragma unroll
        for (int nt = 0; nt < 4; nt++)
#pragma unroll
          for (int i = 0; i < 4; i++)
            smem[(mt * 16 + q * 4 + i) * 128 + col0 + nt * 16] = f2bf(acc[mt][nt][i]);
    }
    __syncthreads();
    const int t = t0 + th;
    for (int cid = tid; cid < 512; cid += 256) {
      const int gsub = cid >> 6;
      const int b = cid & 63;
#pragma unroll
      for (int c = 0; c < 4; c++) {
        union { u16 h[4]; uint2 v; } pk;
#pragma unroll
        for (int gate = 0; gate < 4; gate++) {
          float v = bf2f(smem[b * 128 + gate * 32 + gsub * 4 + c])
                  + bias[gate * 1024 + (g0 + gsub) * 4 + c];
          pk.h[gate] = f2bf(v);
        }
        *(uint2*)(xw + (((size_t)t * 1024 + (g0 + gsub) * 4 + c) * 64 + b) * 4) = pk.v;
      }
    }
  }
}

// ---------- kernel 5: persistent LSTM, 4 groups x 16 batches (R9-VERIFIED, byte-identical) ----------
//   producers: agent write-through h stores (one contiguous 512 B block) -> vmcnt(0) -> flag
//   consumers: wave0 polls own group's 64 flags -> __syncthreads -> sc0 sc1 h loads.
//   split vmcnt(4)/vmcnt(0) around the MFMA halves; xw gates staged into LDS by waves 1-3.
__global__ __launch_bounds__(256, 1) void k_lstm_persist(
    const u16* __restrict__ whT, const u16* __restrict__ xw,
    const int* __restrict__ seq_len, u16* __restrict__ hbuf,
    uint32_t* __restrict__ flags, float* __restrict__ out)
{
  __shared__ float zlds[64 * 66];       // [wave*16+m][66 (pad)]
  __shared__ __align__(8) u16 hpack[16][16];   // [local batch][local hcol]
  __shared__ uint2 xwlds[16][16];       // [local batch][local hcol] 4 gates bf16
  const int gid   = blockIdx.x;
  const int g_grp = gid >> 6;           // batch group 0..3
  const int wg    = gid & 63;           // h-col owner within group
  const int tid   = threadIdx.x;
  const int lane  = tid & 63;
  const int wave  = tid >> 6;
  const int q     = lane >> 4;
  const int col   = lane & 15;
  const int b_t   = tid & 15;           // owned local batch
  const int hc_t  = tid >> 4;           // owned local hcol
  const int g16   = g_grp * 16;

  // stationary weights: wave covers K [wave*256, wave*256+256)
  bf16x8 bw[8][4];
  {
    const u16* wp = whT + (size_t)wg * 65536 + (size_t)(q * 16 + col) * 8;
#pragma unroll
    for (int kt = 0; kt < 8; kt++)
#pragma unroll
      for (int g = 0; g < 4; g++)
        bw[kt][g] = *(const bf16x8*)(wp + (wave * 8 + kt) * 2048 + g * 512);
  }

  const int slen = seq_len[g16 + b_t];
  float c_reg = 0.f, h_reg = 0.f;

  // producer-major A base: producer p = wave*16 + kt*2 + (q>>1), batch = col,
  // elem (q&1)*8 + j. u16 offset: parity*65536 + g_grp*16384 + p*256 + col*16 + (q&1)*8
  const u16* pa0 = hbuf + (size_t)g_grp * 16384
                 + (size_t)(wave * 16 + (q >> 1)) * 256 + col * 16 + (q & 1) * 8;

  auto xw_addr = [&](int t, int hc, int b) {
    return (const uint2*)(xw + (((size_t)t * 1024 + wg * 16 + hc) * 64 + g16 + b) * 4);
  };

  // prologue: fill xwlds for t=0 (waves 1-3; ordered before reads by the t=0 zlds barrier)
  if (wave > 0) {
    const int idx = tid - 64;                     // 0..191
    const int b1 = idx & 15, hc1 = idx >> 4;      // hc 0..11
    xwlds[b1][hc1] = *xw_addr(0, hc1, b1);
    if (idx < 64) {
      const int b2 = idx & 15, hc2 = 12 + (idx >> 4);  // hc 12..15
      xwlds[b2][hc2] = *xw_addr(0, hc2, b2);
    }
  }

  for (int t = 0; t < Tdim; t++) {
    if (t > 0) {
      if (wave == 0) {
        const uint32_t gen = (uint32_t)t;
        const uint32_t* fp = flags + g_grp * 64 + lane;   // all 64 group flags
        uint32_t f;
        do {
          f = __hip_atomic_load(fp, __ATOMIC_RELAXED, __HIP_MEMORY_SCOPE_AGENT);
        } while (!__all(f >= gen));
      }
      __syncthreads();   // R7-verified: barrier between flag observation and h reads
    }

    // coherent (LLC-direct) h loads, producer-major contiguous; av[kt] = 16 B/lane
    const u16* pa_t = pa0 + (size_t)(t & 1) * 65536;
    f32x4 av[8];
#pragma unroll
    for (int kt = 0; kt < 8; kt++)
      asm volatile("global_load_dwordx4 %0, %1, off sc0 sc1"
                   : "=v"(av[kt]) : "v"(pa_t + kt * 512));

    const f32x4 zero4 = {0.f, 0.f, 0.f, 0.f};
    f32x4 acc[4] = {zero4, zero4, zero4, zero4};
    asm volatile("s_waitcnt vmcnt(4)" ::: "memory");
    __builtin_amdgcn_sched_barrier(0);   // rule #18: keep MFMAs behind the wait
#pragma unroll
    for (int kt = 0; kt < 4; kt++)
#pragma unroll
      for (int g = 0; g < 4; g++)
        acc[g] = mfma_bf16(__builtin_bit_cast(bf16x8, av[kt]), bw[kt][g], acc[g]);
    asm volatile("s_waitcnt vmcnt(0)" ::: "memory");
    __builtin_amdgcn_sched_barrier(0);
#pragma unroll
    for (int kt = 4; kt < 8; kt++)
#pragma unroll
      for (int g = 0; g < 4; g++)
        acc[g] = mfma_bf16(__builtin_bit_cast(bf16x8, av[kt]), bw[kt][g], acc[g]);

    // partial z -> LDS (C/D: n = lane&15, m = q*4+i); stride 66 => ~2-way (free)
#pragma unroll
    for (int g = 0; g < 4; g++)
#pragma unroll
      for (int i = 0; i < 4; i++)
        zlds[(wave * 16 + q * 4 + i) * 66 + g * 16 + col] = acc[g][i];
    __syncthreads();

    // cross-wave K-reduction; thread owns (b_t, wg*16 + hc_t)
    float zg[4];
#pragma unroll
    for (int g = 0; g < 4; g++) {
      float s = 0.f;
#pragma unroll
      for (int w = 0; w < 4; w++)
        s += zlds[(w * 16 + b_t) * 66 + g * 16 + hc_t];
      zg[g] = s;
    }
    union { uint2 v; u16 h[4]; } xp; xp.v = xwlds[b_t][hc_t];
    const float zi = zg[0] + bf2f(xp.h[0]);
    const float zj = zg[1] + bf2f(xp.h[1]);
    const float zf = zg[2] + bf2f(xp.h[2]);
    const float zo = zg[3] + bf2f(xp.h[3]);
    if (t < slen) {
      c_reg = c_reg * sigm(zf + 1.0f) + sigm(zi) * tanh_fast(zj);
      h_reg = tanh_fast(c_reg) * sigm(zo);
    }

    if (t == Tdim - 1) break;   // final h stays in registers

    // publish h slice: ONE contiguous 512 B block (4 full lines), drain, then flag
    hpack[b_t][hc_t] = f2bf(h_reg);
    __syncthreads();            // also orders: all zlds/xwlds reads done before rewrites
    if (wave == 0) {
      const int pb = lane >> 2, ph = (lane & 3) * 4;
      const uint64_t pk = *(const uint64_t*)(&hpack[pb][ph]);
      u16* daddr = hbuf + (size_t)((t + 1) & 1) * 65536 + g_grp * 16384
                 + wg * 256 + pb * 16 + ph;
      __hip_atomic_store((uint64_t*)daddr, pk,
                         __ATOMIC_RELAXED, __HIP_MEMORY_SCOPE_AGENT);
      asm volatile("s_waitcnt vmcnt(0)" ::: "memory");   // h at coherence point
      if (lane == 0)
        __hip_atomic_store(flags + gid, (uint32_t)(t + 1),
                           __ATOMIC_RELAXED, __HIP_MEMORY_SCOPE_AGENT);
    }
    // loop bottom: waves 1-3 prefetch xw(t+1) into LDS (hpack barrier ordered the
    // rewrite after all step-t reads; the t+1 poll barrier orders it before reads)
    if (wave > 0) {
      const int idx = tid - 64;
      const int b1 = idx & 15, hc1 = idx >> 4;
      xwlds[b1][hc1] = *xw_addr(t + 1, hc1, b1);
      if (idx < 64) {
        const int b2 = idx & 15, hc2 = 12 + (idx >> 4);
        xwlds[b2][hc2] = *xw_addr(t + 1, hc2, b2);
      }
    }
  }

  out[(size_t)(g16 + b_t) * Hdim + wg * 16 + hc_t] = h_reg;
}

// ---------- host ----------
extern "C" void kernel_launch(void* const* d_in, const int* in_sizes, int n_in,
                              void* d_out, int out_size, void* d_ws, size_t ws_size,
                              hipStream_t stream) {
  (void)in_sizes; (void)n_in; (void)out_size; (void)ws_size;
  const float* x       = (const float*)d_in[0];
  const int*   seq_len = (const int*)d_in[1];
  const float* W       = (const float*)d_in[2];
  const float* bias    = (const float*)d_in[3];
  float* out = (float*)d_out;

  char* ws = (char*)d_ws;
  u16*   xw   = (u16*)(ws);                                  // 128 MB [t][hcol][b][gate] bf16
  u16*   xb   = (u16*)(ws + (size_t)134217728);              // 16 MB  xb2 bf16 [t*64+b][512]
  u16*   wxt  = (u16*)(ws + (size_t)150994944);              // 4 MB   wxt2 bf16 pre-permuted [4096][512]
  u16*   whT  = (u16*)(ws + (size_t)155189248);              // 8 MB   W_h fragments [64][65536]
  char*  hreg = ws + (size_t)163577856;                      // 256 KB h dbuf (producer-major) + flags
  u16*   hbuf = (u16*)hreg;
  uint32_t* flags = (uint32_t*)(hreg + 262144);              // 256 x 4 B packed

  k_init<<<dim3(256), dim3(256), 0, stream>>>((uint64_t*)hreg);          // zero h dbuf + flags
  k_convert_x<<<dim3(8192), dim3(256), 0, stream>>>(x, xb);
  k_transpose_wx<<<dim3(8, 64), dim3(256), 0, stream>>>(W, wxt);
  k_prep_wh<<<dim3(64), dim3(256), 0, stream>>>(W, whT);
  k_gemm_xw<<<dim3(128, 32), dim3(256), 0, stream>>>(xb, wxt, bias, xw);

  {
    void* kargs[] = { (void*)&whT, (void*)&xw, (void*)&seq_len,
                      (void*)&hbuf, (void*)&flags, (void*)&out };
    hipLaunchCooperativeKernel((const void*)k_lstm_persist, dim3(256), dim3(256),
                               kargs, 0, stream);
  }
}

// Round 11
// 896.686 us; speedup vs baseline: 1.8142x; 1.6093x over previous
//
#include <hip/hip_runtime.h>
#include <stdint.h>

typedef unsigned short u16;
typedef __bf16 bf16_t;
typedef bf16_t bf16x8 __attribute__((ext_vector_type(8)));
typedef float f32x4 __attribute__((ext_vector_type(4)));

#define Bdim 64
#define Tdim 256
#define Ddim 512
#define Hdim 1024
#define NGdim 4096

// ---------- helpers ----------
__device__ __forceinline__ u16 f2bf(float f) {
  union { float f; uint32_t u; } v; v.f = f;
  return (u16)((v.u + 0x7FFFu + ((v.u >> 16) & 1u)) >> 16);   // RNE
}
__device__ __forceinline__ float bf2f(u16 h) {
  union { uint32_t u; float f; } v; v.u = ((uint32_t)h) << 16;
  return v.f;
}
__device__ __forceinline__ float sigm(float x) { return 1.0f / (1.0f + __expf(-x)); }
__device__ __forceinline__ float tanh_fast(float x) { return 2.0f / (1.0f + __expf(-2.0f * x)) - 1.0f; }

__device__ __forceinline__ void load_lds16(const void* g, void* l) {
  __builtin_amdgcn_global_load_lds(
      (const __attribute__((address_space(1))) uint32_t*)g,
      (__attribute__((address_space(3))) uint32_t*)l, 16, 0, 0);
}
__device__ __forceinline__ f32x4 mfma_bf16(bf16x8 a, bf16x8 b, f32x4 c) {
  return __builtin_amdgcn_mfma_f32_16x16x32_bf16(a, b, c, 0, 0, 0);
}

// ---------- kernel 0: zero h double-buffer (bf16) + flags region ----------
__global__ void k_init(uint64_t* __restrict__ zreg) {
  zreg[blockIdx.x * 256 + threadIdx.x] = 0ull;   // 256 WGs x 256 x 8 B = 512 KB
}

// ---------- kernel 1: x fp32 [b][t][d] -> xb2 bf16 M-major [t*64+b][512] ----------
__global__ void k_convert_x(const float* __restrict__ x, u16* __restrict__ xb) {
  const int i = (blockIdx.x * 256 + threadIdx.x) * 4;
  const int d = i & 511;
  const int t = (i >> 9) & 255;
  const int b = i >> 17;
  float4 v = *(const float4*)(x + i);
  union { u16 h[4]; uint2 v2; } p;
  p.h[0] = f2bf(v.x); p.h[1] = f2bf(v.y); p.h[2] = f2bf(v.z); p.h[3] = f2bf(v.w);
  *(uint2*)(xb + (size_t)(t * 64 + b) * 512 + d) = p.v2;
}

// ---------- kernel 2: W_h -> per-wg fragment layout whT[wg(64)][kt(32)][gate(4)][q(4)][hc(16)][ki(8)] ----------
// wg owns h-cols [wg*16, wg*16+16). Element (k, gate, hc) = W[(512+k)][gate*1024 + wg*16 + hc].
__global__ void k_prep_wh(const float* __restrict__ W, u16* __restrict__ whT) {
  const int wg = blockIdx.x;           // 0..63
  u16* dst = whT + (size_t)wg * 65536;
  const int gate = threadIdx.x & 3;
  const int hcq  = (threadIdx.x >> 2) & 3;
  const int kb   = threadIdx.x >> 4;   // 0..15
#pragma unroll 1
  for (int kk = 0; kk < 64; kk++) {
    const int k = kb * 64 + kk;
    const float4 wv = *(const float4*)(W + (size_t)(Ddim + k) * NGdim
                                         + gate * 1024 + wg * 16 + hcq * 4);
    const int kt = k >> 5, kl = k & 31, q = kl >> 3, ki = kl & 7;
    const int base = kt * 2048 + gate * 512 + q * 128 + ki;
    dst[base + (hcq * 4 + 0) * 8] = f2bf(wv.x);
    dst[base + (hcq * 4 + 1) * 8] = f2bf(wv.y);
    dst[base + (hcq * 4 + 2) * 8] = f2bf(wv.z);
    dst[base + (hcq * 4 + 3) * 8] = f2bf(wv.w);
  }
}

// ---------- kernel 3: W_x -> per-wg fragment layout whX[wg(64)][kt(16)][gate(4)][q(4)][hc(16)][ki(8)] ----------
// Exact mirror of k_prep_wh with k in [0,512) (W rows 0..511). 64 KB per wg, 4 MB total.
__global__ void k_prep_wx(const float* __restrict__ W, u16* __restrict__ whX) {
  const int wg = blockIdx.x;           // 0..63
  u16* dst = whX + (size_t)wg * 32768;
  const int gate = threadIdx.x & 3;
  const int hcq  = (threadIdx.x >> 2) & 3;
  const int kb   = threadIdx.x >> 4;   // 0..15
#pragma unroll 1
  for (int kk = 0; kk < 32; kk++) {
    const int k = kb * 32 + kk;
    const float4 wv = *(const float4*)(W + (size_t)k * NGdim
                                         + gate * 1024 + wg * 16 + hcq * 4);
    const int kt = k >> 5, kl = k & 31, q = kl >> 3, ki = kl & 7;
    const int base = kt * 2048 + gate * 512 + q * 128 + ki;
    dst[base + (hcq * 4 + 0) * 8] = f2bf(wv.x);
    dst[base + (hcq * 4 + 1) * 8] = f2bf(wv.y);
    dst[base + (hcq * 4 + 2) * 8] = f2bf(wv.z);
    dst[base + (hcq * 4 + 3) * 8] = f2bf(wv.w);
  }
}

// ---------- kernel 4: persistent LSTM with FUSED x@Wx (4 groups x 16 batches) ----------
// Sync protocol byte-identical to R9/R10 (verified): producers publish one contiguous 512 B
// h block (agent write-through) -> vmcnt(0) -> relaxed agent flag; wave0 polls own group's
// 64 flags -> __syncthreads -> sc0 sc1 h loads; split vmcnt(4)/vmcnt(0) around MFMA halves.
// NEW: the x@Wx contribution is computed in-loop BEFORE the poll barrier (h-independent):
// per wave, K_x slice [wave*128,+128), A from xb2 (plain cached loads, read-only), B from
// wxlds (per-WG 64 KB Wx fragment slice staged once into LDS). Accumulates into the SAME
// acc[g] as the h-part, so the zlds reduction + gate path is unchanged. Bias folded into
// the gate step (4 regs/thread). xw buffer / k_gemm_xw / k_transpose_wx are deleted.
__global__ __launch_bounds__(256, 1) void k_lstm_persist(
    const u16* __restrict__ whT, const u16* __restrict__ whX,
    const u16* __restrict__ xb, const int* __restrict__ seq_len,
    u16* __restrict__ hbuf, uint32_t* __restrict__ flags,
    const float* __restrict__ bias, float* __restrict__ out)
{
  __shared__ float zlds[64 * 66];              // [wave*16+m][66 (pad)]
  __shared__ __align__(8) u16 hpack[16][16];   // [local batch][local hcol]
  __shared__ u16 wxlds[32768];                 // 64 KB Wx fragment slice for this wg
  const int gid   = blockIdx.x;
  const int g_grp = gid >> 6;           // batch group 0..3
  const int wg    = gid & 63;           // h-col owner within group
  const int tid   = threadIdx.x;
  const int lane  = tid & 63;
  const int wave  = tid >> 6;
  const int q     = lane >> 4;
  const int col   = lane & 15;
  const int b_t   = tid & 15;           // owned local batch
  const int hc_t  = tid >> 4;           // owned local hcol
  const int g16   = g_grp * 16;

  // stationary W_h weights: wave covers K_h [wave*256, wave*256+256)
  bf16x8 bw[8][4];
  {
    const u16* wp = whT + (size_t)wg * 65536 + (size_t)(q * 16 + col) * 8;
#pragma unroll
    for (int kt = 0; kt < 8; kt++)
#pragma unroll
      for (int g = 0; g < 4; g++)
        bw[kt][g] = *(const bf16x8*)(wp + (wave * 8 + kt) * 2048 + g * 512);
  }

  // stage this wg's Wx fragment slice (64 KB) into LDS, linear copy (16 chunks/wave of 1 KB)
  {
    const u16* src = whX + (size_t)wg * 32768;
#pragma unroll
    for (int i = 0; i < 16; i++) {
      const int chunk = i * 4 + wave;          // 0..63, 512 u16 each
      load_lds16(src + (size_t)chunk * 512 + lane * 8, wxlds + chunk * 512);
    }
  }

  // per-thread bias for owned (hcol, 4 gates)
  float bi[4];
#pragma unroll
  for (int g = 0; g < 4; g++) bi[g] = bias[g * 1024 + wg * 16 + hc_t];

  const int slen = seq_len[g16 + b_t];
  float c_reg = 0.f, h_reg = 0.f;

  // producer-major h base: producer p = wave*16 + kt*2 + (q>>1), batch = col,
  // elem (q&1)*8 + j. u16 offset: parity*65536 + g_grp*16384 + p*256 + col*16 + (q&1)*8
  const u16* pa0 = hbuf + (size_t)g_grp * 16384
                 + (size_t)(wave * 16 + (q >> 1)) * 256 + col * 16 + (q & 1) * 8;
  // x A-frag base: row = t*64 + g16+col (M-major), k = wave*128 + j*32 + q*8
  const u16* px0 = xb + (size_t)(g16 + col) * 512 + wave * 128 + q * 8;

  __syncthreads();   // wxlds staged (compiler drains vmcnt before barrier)

  for (int t = 0; t < Tdim; t++) {
    // ---- x-part (h-independent): overlaps the poll wait ----
    const u16* px = px0 + (size_t)t * 32768;   // t*64 rows * 512
    f32x4 axv[4];
#pragma unroll
    for (int j = 0; j < 4; j++)
      asm volatile("global_load_dwordx4 %0, %1, off" : "=v"(axv[j]) : "v"(px + j * 32));
    asm volatile("s_waitcnt vmcnt(0)" ::: "memory");
    __builtin_amdgcn_sched_barrier(0);

    const f32x4 zero4 = {0.f, 0.f, 0.f, 0.f};
    f32x4 acc[4] = {zero4, zero4, zero4, zero4};
#pragma unroll
    for (int j = 0; j < 4; j++)
#pragma unroll
      for (int g = 0; g < 4; g++) {
        const bf16x8 bx = *(const bf16x8*)(wxlds + (wave * 4 + j) * 2048
                                           + g * 512 + q * 128 + col * 8);
        acc[g] = mfma_bf16(__builtin_bit_cast(bf16x8, axv[j]), bx, acc[g]);
      }

    if (t > 0) {
      if (wave == 0) {
        const uint32_t gen = (uint32_t)t;
        const uint32_t* fp = flags + g_grp * 64 + lane;   // all 64 group flags
        uint32_t f;
        do {
          f = __hip_atomic_load(fp, __ATOMIC_RELAXED, __HIP_MEMORY_SCOPE_AGENT);
        } while (!__all(f >= gen));
      }
      __syncthreads();   // barrier between flag observation and h reads (R7-verified)
    }

    // ---- h-part: coherent (LLC) loads, producer-major contiguous ----
    const u16* pa_t = pa0 + (size_t)(t & 1) * 65536;
    f32x4 av[8];
#pragma unroll
    for (int kt = 0; kt < 8; kt++)
      asm volatile("global_load_dwordx4 %0, %1, off sc0 sc1"
                   : "=v"(av[kt]) : "v"(pa_t + kt * 512));
    asm volatile("s_waitcnt vmcnt(4)" ::: "memory");
    __builtin_amdgcn_sched_barrier(0);   // rule #18
#pragma unroll
    for (int kt = 0; kt < 4; kt++)
#pragma unroll
      for (int g = 0; g < 4; g++)
        acc[g] = mfma_bf16(__builtin_bit_cast(bf16x8, av[kt]), bw[kt][g], acc[g]);
    asm volatile("s_waitcnt vmcnt(0)" ::: "memory");
    __builtin_amdgcn_sched_barrier(0);
#pragma unroll
    for (int kt = 4; kt < 8; kt++)
#pragma unroll
      for (int g = 0; g < 4; g++)
        acc[g] = mfma_bf16(__builtin_bit_cast(bf16x8, av[kt]), bw[kt][g], acc[g]);

    // partial z (x+h) -> LDS (C/D: n = lane&15, m = q*4+i)
#pragma unroll
    for (int g = 0; g < 4; g++)
#pragma unroll
      for (int i = 0; i < 4; i++)
        zlds[(wave * 16 + q * 4 + i) * 66 + g * 16 + col] = acc[g][i];
    __syncthreads();

    // cross-wave K-reduction + bias; thread owns (b_t, wg*16 + hc_t)
    float zg[4];
#pragma unroll
    for (int g = 0; g < 4; g++) {
      float s = bi[g];
#pragma unroll
      for (int w = 0; w < 4; w++)
        s += zlds[(w * 16 + b_t) * 66 + g * 16 + hc_t];
      zg[g] = s;
    }
    if (t < slen) {
      c_reg = c_reg * sigm(zg[2] + 1.0f) + sigm(zg[0]) * tanh_fast(zg[1]);
      h_reg = tanh_fast(c_reg) * sigm(zg[3]);
    }

    if (t == Tdim - 1) break;   // final h stays in registers

    // publish h slice: ONE contiguous 512 B block, drain, then flag (R9-verified)
    hpack[b_t][hc_t] = f2bf(h_reg);
    __syncthreads();            // orders all zlds reads before next-step rewrites
    if (wave == 0) {
      const int pb = lane >> 2, ph = (lane & 3) * 4;
      const uint64_t pk = *(const uint64_t*)(&hpack[pb][ph]);
      u16* daddr = hbuf + (size_t)((t + 1) & 1) * 65536 + g_grp * 16384
                 + wg * 256 + pb * 16 + ph;
      __hip_atomic_store((uint64_t*)daddr, pk,
                         __ATOMIC_RELAXED, __HIP_MEMORY_SCOPE_AGENT);
      asm volatile("s_waitcnt vmcnt(0)" ::: "memory");   // h at coherence point
      if (lane == 0)
        __hip_atomic_store(flags + gid, (uint32_t)(t + 1),
                           __ATOMIC_RELAXED, __HIP_MEMORY_SCOPE_AGENT);
    }
  }

  out[(size_t)(g16 + b_t) * Hdim + wg * 16 + hc_t] = h_reg;
}

// ---------- host ----------
extern "C" void kernel_launch(void* const* d_in, const int* in_sizes, int n_in,
                              void* d_out, int out_size, void* d_ws, size_t ws_size,
                              hipStream_t stream) {
  (void)in_sizes; (void)n_in; (void)out_size; (void)ws_size;
  const float* x       = (const float*)d_in[0];
  const int*   seq_len = (const int*)d_in[1];
  const float* W       = (const float*)d_in[2];
  const float* bias    = (const float*)d_in[3];
  float* out = (float*)d_out;

  char* ws = (char*)d_ws;
  u16*   xb   = (u16*)(ws);                                  // 16 MB  xb2 bf16 [t*64+b][512]
  u16*   whT  = (u16*)(ws + (size_t)16777216);               // 8 MB   W_h fragments [64][65536]
  u16*   whX  = (u16*)(ws + (size_t)25165824);               // 4 MB   W_x fragments [64][32768]
  char*  hreg = ws + (size_t)29360128;                       // 256 KB h dbuf (producer-major) + flags
  u16*   hbuf = (u16*)hreg;
  uint32_t* flags = (uint32_t*)(hreg + 262144);              // 256 x 4 B packed

  k_init<<<dim3(256), dim3(256), 0, stream>>>((uint64_t*)hreg);   // zero h dbuf + flags
  k_convert_x<<<dim3(8192), dim3(256), 0, stream>>>(x, xb);
  k_prep_wh<<<dim3(64), dim3(256), 0, stream>>>(W, whT);
  k_prep_wx<<<dim3(64), dim3(256), 0, stream>>>(W, whX);

  {
    void* kargs[] = { (void*)&whT, (void*)&whX, (void*)&xb, (void*)&seq_len,
                      (void*)&hbuf, (void*)&flags, (void*)&bias, (void*)&out };
    hipLaunchCooperativeKernel((const void*)k_lstm_persist, dim3(256), dim3(256),
                               kargs, 0, stream);
  }
}

// Round 12
// 822.636 us; speedup vs baseline: 1.9775x; 1.0900x over previous
//
#include <hip/hip_runtime.h>
#include <stdint.h>

typedef unsigned short u16;
typedef __bf16 bf16_t;
typedef bf16_t bf16x8 __attribute__((ext_vector_type(8)));
typedef float f32x4 __attribute__((ext_vector_type(4)));

#define Bdim 64
#define Tdim 256
#define Ddim 512
#define Hdim 1024
#define NGdim 4096

// ---------- helpers ----------
__device__ __forceinline__ u16 f2bf(float f) {
  union { float f; uint32_t u; } v; v.f = f;
  return (u16)((v.u + 0x7FFFu + ((v.u >> 16) & 1u)) >> 16);   // RNE
}
__device__ __forceinline__ float bf2f(u16 h) {
  union { uint32_t u; float f; } v; v.u = ((uint32_t)h) << 16;
  return v.f;
}
__device__ __forceinline__ float sigm(float x) { return 1.0f / (1.0f + __expf(-x)); }
__device__ __forceinline__ float tanh_fast(float x) { return 2.0f / (1.0f + __expf(-2.0f * x)) - 1.0f; }

__device__ __forceinline__ void load_lds16(const void* g, void* l) {
  __builtin_amdgcn_global_load_lds(
      (const __attribute__((address_space(1))) uint32_t*)g,
      (__attribute__((address_space(3))) uint32_t*)l, 16, 0, 0);
}
__device__ __forceinline__ f32x4 mfma_bf16(bf16x8 a, bf16x8 b, f32x4 c) {
  return __builtin_amdgcn_mfma_f32_16x16x32_bf16(a, b, c, 0, 0, 0);
}

// ---------- kernel 0: zero h double-buffer (bf16) + flags region ----------
__global__ void k_init(uint64_t* __restrict__ zreg) {
  zreg[blockIdx.x * 256 + threadIdx.x] = 0ull;   // 256 WGs x 256 x 8 B = 512 KB
}

// ---------- kernel 1: x fp32 [b][t][d] -> xb2 bf16 M-major [t*64+b][512] ----------
__global__ void k_convert_x(const float* __restrict__ x, u16* __restrict__ xb) {
  const int i = (blockIdx.x * 256 + threadIdx.x) * 4;
  const int d = i & 511;
  const int t = (i >> 9) & 255;
  const int b = i >> 17;
  float4 v = *(const float4*)(x + i);
  union { u16 h[4]; uint2 v2; } p;
  p.h[0] = f2bf(v.x); p.h[1] = f2bf(v.y); p.h[2] = f2bf(v.z); p.h[3] = f2bf(v.w);
  *(uint2*)(xb + (size_t)(t * 64 + b) * 512 + d) = p.v2;
}

// ---------- kernel 2: W_h -> whT[wg(64)][kt(32)][gate(4)][q(4)][hc(16)][ki(8)]  (coalesced rewrite) ----------
// Output contents IDENTICAL to the R11-verified mapping:
//   whT[wg*65536 + kt*2048 + gate*512 + q*128 + hc*8 + ki] = bf16(W[(512+kt*32+q*8+ki)*4096
//                                                                   + gate*1024 + wg*16 + hc])
// LDS-staged: load 32x64 f32 tile of W (64-B bursts), then each thread gathers 8 k-consecutive
// elements and emits ONE uint4 (consecutive threads -> consecutive 16 B = coalesced).
// Grid 256: wg = bid>>2, kt in [(bid&3)*8, +8).
__global__ void k_prep_wh(const float* __restrict__ W, u16* __restrict__ whT) {
  __shared__ float tile[32][68];
  const int wg  = blockIdx.x >> 2;
  const int ktg = blockIdx.x & 3;
  const int tid = threadIdx.x;
  const int lr = tid >> 3, lg = (tid >> 1) & 3, ls = (tid & 1) * 2;   // load: row, gate, sub
  const int gate = tid >> 6, q = (tid >> 4) & 3, hc = tid & 15;       // write mapping
#pragma unroll 1
  for (int kt = ktg * 8; kt < ktg * 8 + 8; kt++) {
    __syncthreads();
    {
      const float* src = W + (size_t)(Ddim + kt * 32 + lr) * NGdim + lg * 1024 + wg * 16 + ls * 4;
      const float4 v0 = *(const float4*)(src);
      const float4 v1 = *(const float4*)(src + 4);
      *(float4*)&tile[lr][lg * 16 + ls * 4]     = v0;
      *(float4*)&tile[lr][lg * 16 + ls * 4 + 4] = v1;
    }
    __syncthreads();
    union { u16 h[8]; uint4 v; } p;
#pragma unroll
    for (int ki = 0; ki < 8; ki++) p.h[ki] = f2bf(tile[q * 8 + ki][gate * 16 + hc]);
    *(uint4*)(whT + (size_t)wg * 65536 + kt * 2048 + gate * 512 + q * 128 + hc * 8) = p.v;
  }
}

// ---------- kernel 3: W_x -> whX[wg(64)][kt(16)][gate(4)][q(4)][hc(16)][ki(8)]  (coalesced rewrite) ----------
// Same structure, W rows [0,512). Grid 256: wg = bid>>2, kt in [(bid&3)*4, +4).
__global__ void k_prep_wx(const float* __restrict__ W, u16* __restrict__ whX) {
  __shared__ float tile[32][68];
  const int wg  = blockIdx.x >> 2;
  const int ktg = blockIdx.x & 3;
  const int tid = threadIdx.x;
  const int lr = tid >> 3, lg = (tid >> 1) & 3, ls = (tid & 1) * 2;
  const int gate = tid >> 6, q = (tid >> 4) & 3, hc = tid & 15;
#pragma unroll 1
  for (int kt = ktg * 4; kt < ktg * 4 + 4; kt++) {
    __syncthreads();
    {
      const float* src = W + (size_t)(kt * 32 + lr) * NGdim + lg * 1024 + wg * 16 + ls * 4;
      const float4 v0 = *(const float4*)(src);
      const float4 v1 = *(const float4*)(src + 4);
      *(float4*)&tile[lr][lg * 16 + ls * 4]     = v0;
      *(float4*)&tile[lr][lg * 16 + ls * 4 + 4] = v1;
    }
    __syncthreads();
    union { u16 h[8]; uint4 v; } p;
#pragma unroll
    for (int ki = 0; ki < 8; ki++) p.h[ki] = f2bf(tile[q * 8 + ki][gate * 16 + hc]);
    *(uint4*)(whX + (size_t)wg * 32768 + kt * 2048 + gate * 512 + q * 128 + hc * 8) = p.v;
  }
}

// ---------- kernel 4: persistent LSTM with FUSED x@Wx (R11-VERIFIED, byte-identical) ----------
// Sync protocol: producers publish one contiguous 512 B h block (agent write-through) ->
// vmcnt(0) -> relaxed agent flag; wave0 polls own group's 64 flags -> __syncthreads ->
// sc0 sc1 h loads; split vmcnt(4)/vmcnt(0) around MFMA halves. x@Wx computed in-loop
// before the poll (h-independent), accumulating into the same acc[g].
__global__ __launch_bounds__(256, 1) void k_lstm_persist(
    const u16* __restrict__ whT, const u16* __restrict__ whX,
    const u16* __restrict__ xb, const int* __restrict__ seq_len,
    u16* __restrict__ hbuf, uint32_t* __restrict__ flags,
    const float* __restrict__ bias, float* __restrict__ out)
{
  __shared__ float zlds[64 * 66];              // [wave*16+m][66 (pad)]
  __shared__ __align__(8) u16 hpack[16][16];   // [local batch][local hcol]
  __shared__ u16 wxlds[32768];                 // 64 KB Wx fragment slice for this wg
  const int gid   = blockIdx.x;
  const int g_grp = gid >> 6;           // batch group 0..3
  const int wg    = gid & 63;           // h-col owner within group
  const int tid   = threadIdx.x;
  const int lane  = tid & 63;
  const int wave  = tid >> 6;
  const int q     = lane >> 4;
  const int col   = lane & 15;
  const int b_t   = tid & 15;           // owned local batch
  const int hc_t  = tid >> 4;           // owned local hcol
  const int g16   = g_grp * 16;

  // stationary W_h weights: wave covers K_h [wave*256, wave*256+256)
  bf16x8 bw[8][4];
  {
    const u16* wp = whT + (size_t)wg * 65536 + (size_t)(q * 16 + col) * 8;
#pragma unroll
    for (int kt = 0; kt < 8; kt++)
#pragma unroll
      for (int g = 0; g < 4; g++)
        bw[kt][g] = *(const bf16x8*)(wp + (wave * 8 + kt) * 2048 + g * 512);
  }

  // stage this wg's Wx fragment slice (64 KB) into LDS, linear copy (16 chunks/wave of 1 KB)
  {
    const u16* src = whX + (size_t)wg * 32768;
#pragma unroll
    for (int i = 0; i < 16; i++) {
      const int chunk = i * 4 + wave;          // 0..63, 512 u16 each
      load_lds16(src + (size_t)chunk * 512 + lane * 8, wxlds + chunk * 512);
    }
  }

  // per-thread bias for owned (hcol, 4 gates)
  float bi[4];
#pragma unroll
  for (int g = 0; g < 4; g++) bi[g] = bias[g * 1024 + wg * 16 + hc_t];

  const int slen = seq_len[g16 + b_t];
  float c_reg = 0.f, h_reg = 0.f;

  // producer-major h base: producer p = wave*16 + kt*2 + (q>>1), batch = col,
  // elem (q&1)*8 + j. u16 offset: parity*65536 + g_grp*16384 + p*256 + col*16 + (q&1)*8
  const u16* pa0 = hbuf + (size_t)g_grp * 16384
                 + (size_t)(wave * 16 + (q >> 1)) * 256 + col * 16 + (q & 1) * 8;
  // x A-frag base: row = t*64 + g16+col (M-major), k = wave*128 + j*32 + q*8
  const u16* px0 = xb + (size_t)(g16 + col) * 512 + wave * 128 + q * 8;

  __syncthreads();   // wxlds staged (compiler drains vmcnt before barrier)

  for (int t = 0; t < Tdim; t++) {
    // ---- x-part (h-independent): overlaps the poll wait ----
    const u16* px = px0 + (size_t)t * 32768;   // t*64 rows * 512
    f32x4 axv[4];
#pragma unroll
    for (int j = 0; j < 4; j++)
      asm volatile("global_load_dwordx4 %0, %1, off" : "=v"(axv[j]) : "v"(px + j * 32));
    asm volatile("s_waitcnt vmcnt(0)" ::: "memory");
    __builtin_amdgcn_sched_barrier(0);

    const f32x4 zero4 = {0.f, 0.f, 0.f, 0.f};
    f32x4 acc[4] = {zero4, zero4, zero4, zero4};
#pragma unroll
    for (int j = 0; j < 4; j++)
#pragma unroll
      for (int g = 0; g < 4; g++) {
        const bf16x8 bx = *(const bf16x8*)(wxlds + (wave * 4 + j) * 2048
                                           + g * 512 + q * 128 + col * 8);
        acc[g] = mfma_bf16(__builtin_bit_cast(bf16x8, axv[j]), bx, acc[g]);
      }

    if (t > 0) {
      if (wave == 0) {
        const uint32_t gen = (uint32_t)t;
        const uint32_t* fp = flags + g_grp * 64 + lane;   // all 64 group flags
        uint32_t f;
        do {
          f = __hip_atomic_load(fp, __ATOMIC_RELAXED, __HIP_MEMORY_SCOPE_AGENT);
        } while (!__all(f >= gen));
      }
      __syncthreads();   // barrier between flag observation and h reads (R7-verified)
    }

    // ---- h-part: coherent (LLC) loads, producer-major contiguous ----
    const u16* pa_t = pa0 + (size_t)(t & 1) * 65536;
    f32x4 av[8];
#pragma unroll
    for (int kt = 0; kt < 8; kt++)
      asm volatile("global_load_dwordx4 %0, %1, off sc0 sc1"
                   : "=v"(av[kt]) : "v"(pa_t + kt * 512));
    asm volatile("s_waitcnt vmcnt(4)" ::: "memory");
    __builtin_amdgcn_sched_barrier(0);   // rule #18
#pragma unroll
    for (int kt = 0; kt < 4; kt++)
#pragma unroll
      for (int g = 0; g < 4; g++)
        acc[g] = mfma_bf16(__builtin_bit_cast(bf16x8, av[kt]), bw[kt][g], acc[g]);
    asm volatile("s_waitcnt vmcnt(0)" ::: "memory");
    __builtin_amdgcn_sched_barrier(0);
#pragma unroll
    for (int kt = 4; kt < 8; kt++)
#pragma unroll
      for (int g = 0; g < 4; g++)
        acc[g] = mfma_bf16(__builtin_bit_cast(bf16x8, av[kt]), bw[kt][g], acc[g]);

    // partial z (x+h) -> LDS (C/D: n = lane&15, m = q*4+i)
#pragma unroll
    for (int g = 0; g < 4; g++)
#pragma unroll
      for (int i = 0; i < 4; i++)
        zlds[(wave * 16 + q * 4 + i) * 66 + g * 16 + col] = acc[g][i];
    __syncthreads();

    // cross-wave K-reduction + bias; thread owns (b_t, wg*16 + hc_t)
    float zg[4];
#pragma unroll
    for (int g = 0; g < 4; g++) {
      float s = bi[g];
#pragma unroll
      for (int w = 0; w < 4; w++)
        s += zlds[(w * 16 + b_t) * 66 + g * 16 + hc_t];
      zg[g] = s;
    }
    if (t < slen) {
      c_reg = c_reg * sigm(zg[2] + 1.0f) + sigm(zg[0]) * tanh_fast(zg[1]);
      h_reg = tanh_fast(c_reg) * sigm(zg[3]);
    }

    if (t == Tdim - 1) break;   // final h stays in registers

    // publish h slice: ONE contiguous 512 B block, drain, then flag (R9-verified)
    hpack[b_t][hc_t] = f2bf(h_reg);
    __syncthreads();            // orders all zlds reads before next-step rewrites
    if (wave == 0) {
      const int pb = lane >> 2, ph = (lane & 3) * 4;
      const uint64_t pk = *(const uint64_t*)(&hpack[pb][ph]);
      u16* daddr = hbuf + (size_t)((t + 1) & 1) * 65536 + g_grp * 16384
                 + wg * 256 + pb * 16 + ph;
      __hip_atomic_store((uint64_t*)daddr, pk,
                         __ATOMIC_RELAXED, __HIP_MEMORY_SCOPE_AGENT);
      asm volatile("s_waitcnt vmcnt(0)" ::: "memory");   // h at coherence point
      if (lane == 0)
        __hip_atomic_store(flags + gid, (uint32_t)(t + 1),
                           __ATOMIC_RELAXED, __HIP_MEMORY_SCOPE_AGENT);
    }
  }

  out[(size_t)(g16 + b_t) * Hdim + wg * 16 + hc_t] = h_reg;
}

// ---------- host ----------
extern "C" void kernel_launch(void* const* d_in, const int* in_sizes, int n_in,
                              void* d_out, int out_size, void* d_ws, size_t ws_size,
                              hipStream_t stream) {
  (void)in_sizes; (void)n_in; (void)out_size; (void)ws_size;
  const float* x       = (const float*)d_in[0];
  const int*   seq_len = (const int*)d_in[1];
  const float* W       = (const float*)d_in[2];
  const float* bias    = (const float*)d_in[3];
  float* out = (float*)d_out;

  char* ws = (char*)d_ws;
  u16*   xb   = (u16*)(ws);                                  // 16 MB  xb2 bf16 [t*64+b][512]
  u16*   whT  = (u16*)(ws + (size_t)16777216);               // 8 MB   W_h fragments [64][65536]
  u16*   whX  = (u16*)(ws + (size_t)25165824);               // 4 MB   W_x fragments [64][32768]
  char*  hreg = ws + (size_t)29360128;                       // 256 KB h dbuf (producer-major) + flags
  u16*   hbuf = (u16*)hreg;
  uint32_t* flags = (uint32_t*)(hreg + 262144);              // 256 x 4 B packed

  k_init<<<dim3(256), dim3(256), 0, stream>>>((uint64_t*)hreg);   // zero h dbuf + flags
  k_convert_x<<<dim3(8192), dim3(256), 0, stream>>>(x, xb);
  k_prep_wh<<<dim3(256), dim3(256), 0, stream>>>(W, whT);
  k_prep_wx<<<dim3(256), dim3(256), 0, stream>>>(W, whX);

  {
    void* kargs[] = { (void*)&whT, (void*)&whX, (void*)&xb, (void*)&seq_len,
                      (void*)&hbuf, (void*)&flags, (void*)&bias, (void*)&out };
    hipLaunchCooperativeKernel((const void*)k_lstm_persist, dim3(256), dim3(256),
                               kargs, 0, stream);
  }
}

// Round 13
// 815.679 us; speedup vs baseline: 1.9943x; 1.0085x over previous
//
#include <hip/hip_runtime.h>
#include <stdint.h>

typedef unsigned short u16;
typedef __bf16 bf16_t;
typedef bf16_t bf16x8 __attribute__((ext_vector_type(8)));
typedef float f32x4 __attribute__((ext_vector_type(4)));

#define Bdim 64
#define Tdim 256
#define Ddim 512
#define Hdim 1024
#define NGdim 4096

// ---------- helpers ----------
__device__ __forceinline__ u16 f2bf(float f) {
  union { float f; uint32_t u; } v; v.f = f;
  return (u16)((v.u + 0x7FFFu + ((v.u >> 16) & 1u)) >> 16);   // RNE
}
__device__ __forceinline__ float bf2f(u16 h) {
  union { uint32_t u; float f; } v; v.u = ((uint32_t)h) << 16;
  return v.f;
}
__device__ __forceinline__ float sigm(float x) { return 1.0f / (1.0f + __expf(-x)); }
__device__ __forceinline__ float tanh_fast(float x) { return 2.0f / (1.0f + __expf(-2.0f * x)) - 1.0f; }

__device__ __forceinline__ void load_lds16(const void* g, void* l) {
  __builtin_amdgcn_global_load_lds(
      (const __attribute__((address_space(1))) uint32_t*)g,
      (__attribute__((address_space(3))) uint32_t*)l, 16, 0, 0);
}
__device__ __forceinline__ f32x4 mfma_bf16(bf16x8 a, bf16x8 b, f32x4 c) {
  return __builtin_amdgcn_mfma_f32_16x16x32_bf16(a, b, c, 0, 0, 0);
}

// ---------- kernel 1: merged setup (one launch, 8192 blocks) ----------
// All blocks: x fp32 [b][t][d] -> xb2 bf16 M-major [t*64+b][512]  (R12-verified math).
// Blocks 0..255:   prep_wh chunk (wg = bid>>2, ktg = bid&3)       (R12-verified math).
// Blocks 256..511: prep_wx chunk (wg = (bid-256)>>2, ktg = ...)   (R12-verified math).
// Blocks 512..767: zero h dbuf + flags region (512 KB).
// The three extra roles are mutually independent and independent of the convert
// (disjoint inputs/outputs); __syncthreads in prep branches is blockIdx-uniform.
__global__ __launch_bounds__(256) void k_setup(
    const float* __restrict__ x, u16* __restrict__ xb,
    const float* __restrict__ W, u16* __restrict__ whT, u16* __restrict__ whX,
    uint64_t* __restrict__ zreg)
{
  __shared__ float tile[32][68];
  const int bid = blockIdx.x;
  const int tid = threadIdx.x;

  // ---- convert slice (every block) ----
  {
    const int i = (bid * 256 + tid) * 4;
    const int d = i & 511;
    const int t = (i >> 9) & 255;
    const int b = i >> 17;
    float4 v = *(const float4*)(x + i);
    union { u16 h[4]; uint2 v2; } p;
    p.h[0] = f2bf(v.x); p.h[1] = f2bf(v.y); p.h[2] = f2bf(v.z); p.h[3] = f2bf(v.w);
    *(uint2*)(xb + (size_t)(t * 64 + b) * 512 + d) = p.v2;
  }

  if (bid < 256) {
    // ---- prep_wh: whT[wg*65536 + kt*2048 + gate*512 + q*128 + hc*8 + ki]
    //              = bf16(W[(512+kt*32+q*8+ki)*4096 + gate*1024 + wg*16 + hc]) ----
    const int wg  = bid >> 2;
    const int ktg = bid & 3;
    const int lr = tid >> 3, lg = (tid >> 1) & 3, ls = (tid & 1) * 2;
    const int gate = tid >> 6, q = (tid >> 4) & 3, hc = tid & 15;
#pragma unroll 1
    for (int kt = ktg * 8; kt < ktg * 8 + 8; kt++) {
      __syncthreads();
      {
        const float* src = W + (size_t)(Ddim + kt * 32 + lr) * NGdim + lg * 1024 + wg * 16 + ls * 4;
        const float4 v0 = *(const float4*)(src);
        const float4 v1 = *(const float4*)(src + 4);
        *(float4*)&tile[lr][lg * 16 + ls * 4]     = v0;
        *(float4*)&tile[lr][lg * 16 + ls * 4 + 4] = v1;
      }
      __syncthreads();
      union { u16 h[8]; uint4 v; } p;
#pragma unroll
      for (int ki = 0; ki < 8; ki++) p.h[ki] = f2bf(tile[q * 8 + ki][gate * 16 + hc]);
      *(uint4*)(whT + (size_t)wg * 65536 + kt * 2048 + gate * 512 + q * 128 + hc * 8) = p.v;
    }
  } else if (bid < 512) {
    // ---- prep_wx: same structure, W rows [0,512) ----
    const int b2  = bid - 256;
    const int wg  = b2 >> 2;
    const int ktg = b2 & 3;
    const int lr = tid >> 3, lg = (tid >> 1) & 3, ls = (tid & 1) * 2;
    const int gate = tid >> 6, q = (tid >> 4) & 3, hc = tid & 15;
#pragma unroll 1
    for (int kt = ktg * 4; kt < ktg * 4 + 4; kt++) {
      __syncthreads();
      {
        const float* src = W + (size_t)(kt * 32 + lr) * NGdim + lg * 1024 + wg * 16 + ls * 4;
        const float4 v0 = *(const float4*)(src);
        const float4 v1 = *(const float4*)(src + 4);
        *(float4*)&tile[lr][lg * 16 + ls * 4]     = v0;
        *(float4*)&tile[lr][lg * 16 + ls * 4 + 4] = v1;
      }
      __syncthreads();
      union { u16 h[8]; uint4 v; } p;
#pragma unroll
      for (int ki = 0; ki < 8; ki++) p.h[ki] = f2bf(tile[q * 8 + ki][gate * 16 + hc]);
      *(uint4*)(whX + (size_t)wg * 32768 + kt * 2048 + gate * 512 + q * 128 + hc * 8) = p.v;
    }
  } else if (bid < 768) {
    // ---- zero h dbuf + flags (512 KB) ----
    zreg[(size_t)(bid - 512) * 256 + tid] = 0ull;
  }
}

// ---------- kernel 2: persistent LSTM with FUSED x@Wx (R11/R12-VERIFIED, byte-identical) ----------
// Sync protocol: producers publish one contiguous 512 B h block (agent write-through) ->
// vmcnt(0) -> relaxed agent flag; wave0 polls own group's 64 flags -> __syncthreads ->
// sc0 sc1 h loads; split vmcnt(4)/vmcnt(0) around MFMA halves. x@Wx computed in-loop
// before the poll (h-independent), accumulating into the same acc[g].
__global__ __launch_bounds__(256, 1) void k_lstm_persist(
    const u16* __restrict__ whT, const u16* __restrict__ whX,
    const u16* __restrict__ xb, const int* __restrict__ seq_len,
    u16* __restrict__ hbuf, uint32_t* __restrict__ flags,
    const float* __restrict__ bias, float* __restrict__ out)
{
  __shared__ float zlds[64 * 66];              // [wave*16+m][66 (pad)]
  __shared__ __align__(8) u16 hpack[16][16];   // [local batch][local hcol]
  __shared__ u16 wxlds[32768];                 // 64 KB Wx fragment slice for this wg
  const int gid   = blockIdx.x;
  const int g_grp = gid >> 6;           // batch group 0..3
  const int wg    = gid & 63;           // h-col owner within group
  const int tid   = threadIdx.x;
  const int lane  = tid & 63;
  const int wave  = tid >> 6;
  const int q     = lane >> 4;
  const int col   = lane & 15;
  const int b_t   = tid & 15;           // owned local batch
  const int hc_t  = tid >> 4;           // owned local hcol
  const int g16   = g_grp * 16;

  // stationary W_h weights: wave covers K_h [wave*256, wave*256+256)
  bf16x8 bw[8][4];
  {
    const u16* wp = whT + (size_t)wg * 65536 + (size_t)(q * 16 + col) * 8;
#pragma unroll
    for (int kt = 0; kt < 8; kt++)
#pragma unroll
      for (int g = 0; g < 4; g++)
        bw[kt][g] = *(const bf16x8*)(wp + (wave * 8 + kt) * 2048 + g * 512);
  }

  // stage this wg's Wx fragment slice (64 KB) into LDS, linear copy (16 chunks/wave of 1 KB)
  {
    const u16* src = whX + (size_t)wg * 32768;
#pragma unroll
    for (int i = 0; i < 16; i++) {
      const int chunk = i * 4 + wave;          // 0..63, 512 u16 each
      load_lds16(src + (size_t)chunk * 512 + lane * 8, wxlds + chunk * 512);
    }
  }

  // per-thread bias for owned (hcol, 4 gates)
  float bi[4];
#pragma unroll
  for (int g = 0; g < 4; g++) bi[g] = bias[g * 1024 + wg * 16 + hc_t];

  const int slen = seq_len[g16 + b_t];
  float c_reg = 0.f, h_reg = 0.f;

  // producer-major h base: producer p = wave*16 + kt*2 + (q>>1), batch = col,
  // elem (q&1)*8 + j. u16 offset: parity*65536 + g_grp*16384 + p*256 + col*16 + (q&1)*8
  const u16* pa0 = hbuf + (size_t)g_grp * 16384
                 + (size_t)(wave * 16 + (q >> 1)) * 256 + col * 16 + (q & 1) * 8;
  // x A-frag base: row = t*64 + g16+col (M-major), k = wave*128 + j*32 + q*8
  const u16* px0 = xb + (size_t)(g16 + col) * 512 + wave * 128 + q * 8;

  __syncthreads();   // wxlds staged (compiler drains vmcnt before barrier)

  for (int t = 0; t < Tdim; t++) {
    // ---- x-part (h-independent): overlaps the poll wait ----
    const u16* px = px0 + (size_t)t * 32768;   // t*64 rows * 512
    f32x4 axv[4];
#pragma unroll
    for (int j = 0; j < 4; j++)
      asm volatile("global_load_dwordx4 %0, %1, off" : "=v"(axv[j]) : "v"(px + j * 32));
    asm volatile("s_waitcnt vmcnt(0)" ::: "memory");
    __builtin_amdgcn_sched_barrier(0);

    const f32x4 zero4 = {0.f, 0.f, 0.f, 0.f};
    f32x4 acc[4] = {zero4, zero4, zero4, zero4};
#pragma unroll
    for (int j = 0; j < 4; j++)
#pragma unroll
      for (int g = 0; g < 4; g++) {
        const bf16x8 bx = *(const bf16x8*)(wxlds + (wave * 4 + j) * 2048
                                           + g * 512 + q * 128 + col * 8);
        acc[g] = mfma_bf16(__builtin_bit_cast(bf16x8, axv[j]), bx, acc[g]);
      }

    if (t > 0) {
      if (wave == 0) {
        const uint32_t gen = (uint32_t)t;
        const uint32_t* fp = flags + g_grp * 64 + lane;   // all 64 group flags
        uint32_t f;
        do {
          f = __hip_atomic_load(fp, __ATOMIC_RELAXED, __HIP_MEMORY_SCOPE_AGENT);
        } while (!__all(f >= gen));
      }
      __syncthreads();   // barrier between flag observation and h reads (R7-verified)
    }

    // ---- h-part: coherent (LLC) loads, producer-major contiguous ----
    const u16* pa_t = pa0 + (size_t)(t & 1) * 65536;
    f32x4 av[8];
#pragma unroll
    for (int kt = 0; kt < 8; kt++)
      asm volatile("global_load_dwordx4 %0, %1, off sc0 sc1"
                   : "=v"(av[kt]) : "v"(pa_t + kt * 512));
    asm volatile("s_waitcnt vmcnt(4)" ::: "memory");
    __builtin_amdgcn_sched_barrier(0);   // rule #18
#pragma unroll
    for (int kt = 0; kt < 4; kt++)
#pragma unroll
      for (int g = 0; g < 4; g++)
        acc[g] = mfma_bf16(__builtin_bit_cast(bf16x8, av[kt]), bw[kt][g], acc[g]);
    asm volatile("s_waitcnt vmcnt(0)" ::: "memory");
    __builtin_amdgcn_sched_barrier(0);
#pragma unroll
    for (int kt = 4; kt < 8; kt++)
#pragma unroll
      for (int g = 0; g < 4; g++)
        acc[g] = mfma_bf16(__builtin_bit_cast(bf16x8, av[kt]), bw[kt][g], acc[g]);

    // partial z (x+h) -> LDS (C/D: n = lane&15, m = q*4+i)
#pragma unroll
    for (int g = 0; g < 4; g++)
#pragma unroll
      for (int i = 0; i < 4; i++)
        zlds[(wave * 16 + q * 4 + i) * 66 + g * 16 + col] = acc[g][i];
    __syncthreads();

    // cross-wave K-reduction + bias; thread owns (b_t, wg*16 + hc_t)
    float zg[4];
#pragma unroll
    for (int g = 0; g < 4; g++) {
      float s = bi[g];
#pragma unroll
      for (int w = 0; w < 4; w++)
        s += zlds[(w * 16 + b_t) * 66 + g * 16 + hc_t];
      zg[g] = s;
    }
    if (t < slen) {
      c_reg = c_reg * sigm(zg[2] + 1.0f) + sigm(zg[0]) * tanh_fast(zg[1]);
      h_reg = tanh_fast(c_reg) * sigm(zg[3]);
    }

    if (t == Tdim - 1) break;   // final h stays in registers

    // publish h slice: ONE contiguous 512 B block, drain, then flag (R9-verified)
    hpack[b_t][hc_t] = f2bf(h_reg);
    __syncthreads();            // orders all zlds reads before next-step rewrites
    if (wave == 0) {
      const int pb = lane >> 2, ph = (lane & 3) * 4;
      const uint64_t pk = *(const uint64_t*)(&hpack[pb][ph]);
      u16* daddr = hbuf + (size_t)((t + 1) & 1) * 65536 + g_grp * 16384
                 + wg * 256 + pb * 16 + ph;
      __hip_atomic_store((uint64_t*)daddr, pk,
                         __ATOMIC_RELAXED, __HIP_MEMORY_SCOPE_AGENT);
      asm volatile("s_waitcnt vmcnt(0)" ::: "memory");   // h at coherence point
      if (lane == 0)
        __hip_atomic_store(flags + gid, (uint32_t)(t + 1),
                           __ATOMIC_RELAXED, __HIP_MEMORY_SCOPE_AGENT);
    }
  }

  out[(size_t)(g16 + b_t) * Hdim + wg * 16 + hc_t] = h_reg;
}

// ---------- host ----------
extern "C" void kernel_launch(void* const* d_in, const int* in_sizes, int n_in,
                              void* d_out, int out_size, void* d_ws, size_t ws_size,
                              hipStream_t stream) {
  (void)in_sizes; (void)n_in; (void)out_size; (void)ws_size;
  const float* x       = (const float*)d_in[0];
  const int*   seq_len = (const int*)d_in[1];
  const float* W       = (const float*)d_in[2];
  const float* bias    = (const float*)d_in[3];
  float* out = (float*)d_out;

  char* ws = (char*)d_ws;
  u16*   xb   = (u16*)(ws);                                  // 16 MB  xb2 bf16 [t*64+b][512]
  u16*   whT  = (u16*)(ws + (size_t)16777216);               // 8 MB   W_h fragments [64][65536]
  u16*   whX  = (u16*)(ws + (size_t)25165824);               // 4 MB   W_x fragments [64][32768]
  char*  hreg = ws + (size_t)29360128;                       // 256 KB h dbuf (producer-major) + flags
  u16*   hbuf = (u16*)hreg;
  uint32_t* flags = (uint32_t*)(hreg + 262144);              // 256 x 4 B packed

  k_setup<<<dim3(8192), dim3(256), 0, stream>>>(x, xb, W, whT, whX, (uint64_t*)hreg);

  {
    void* kargs[] = { (void*)&whT, (void*)&whX, (void*)&xb, (void*)&seq_len,
                      (void*)&hbuf, (void*)&flags, (void*)&bias, (void*)&out };
    hipLaunchCooperativeKernel((const void*)k_lstm_persist, dim3(256), dim3(256),
                               kargs, 0, stream);
  }
}